// Round 5
// baseline (753.759 us; speedup 1.0000x reference)
//
#include <hip/hip_runtime.h>
#include <hip/hip_bf16.h>

#define HDIM 128
#define NSTAGE 7
#define CHUNK_LOG 13
#define CHUNK (1 << CHUNK_LOG)

typedef __bf16 bf16x8 __attribute__((ext_vector_type(8)));
typedef __bf16 bf16x2 __attribute__((ext_vector_type(2)));
typedef float floatx16 __attribute__((ext_vector_type(16)));
typedef float floatx4 __attribute__((ext_vector_type(4)));
typedef int intx4 __attribute__((ext_vector_type(4)));

__device__ __forceinline__ float silu_f(float x) {
    return x * __builtin_amdgcn_rcpf(1.0f + __expf(-x));
}

__device__ __forceinline__ int pack2(float a, float b) {
    bf16x2 h;
    h[0] = (__bf16)a;
    h[1] = (__bf16)b;
    return __builtin_bit_cast(int, h);
}

__device__ __forceinline__ bf16x8 frag_from(int w0, int w1, int w2, int w3) {
    intx4 v; v[0] = w0; v[1] = w1; v[2] = w2; v[3] = w3;
    return __builtin_bit_cast(bf16x8, v);
}

// async global->LDS, 16B per lane; LDS dest = wave-uniform base + lane*16.
__device__ __forceinline__ void gload_lds16(const void* g, void* l) {
    __builtin_amdgcn_global_load_lds(
        (const __attribute__((address_space(1))) unsigned int*)g,
        (__attribute__((address_space(3))) unsigned int*)l, 16, 0, 0);
}

// Weights -> bf16, stage order W1[0],W2[0],W1[1],W2[1],W1[2],W2[2],Wlin.
// XOR swizzle on 16B chunks: [m][k] -> m*128 + ((k>>3)^(m&7))*8 + (k&7).
__global__ void convert_weights(const float* __restrict__ W1,
                                const float* __restrict__ W2,
                                const float* __restrict__ Wlin,
                                __bf16* __restrict__ dst) {
    int idx = blockIdx.x * blockDim.x + threadIdx.x;
    if (idx >= NSTAGE * HDIM * HDIM) return;
    int s    = idx >> 14;
    int rem  = idx & 16383;
    int mrow = rem >> 7;
    int k    = rem & 127;
    const float* src;
    if (s == 6) src = Wlin;
    else {
        int l = s >> 1;
        src = ((s & 1) ? W2 : W1) + l * HDIM * HDIM;
    }
    float v = src[mrow * HDIM + k];
    int dsti = (s << 14) + (mrow << 7) + ((((k >> 3) ^ (mrow & 7)) << 3) | (k & 7));
    dst[dsti] = (__bf16)v;
}

// ---- atomic-free counting sort of edges by target node ----
__global__ __launch_bounds__(1024) void hist_rank_kernel(
    const int* __restrict__ tgt,
    unsigned short* __restrict__ rank,
    int* __restrict__ hb,
    int E, int N)
{
    __shared__ int lh[10240];   // N = 10000 for this problem
    for (int i = threadIdx.x; i < N; i += 1024) lh[i] = 0;
    __syncthreads();
    int ebase = blockIdx.x << CHUNK_LOG;
    int eend  = min(ebase + CHUNK, E);
    for (int e = ebase + (int)threadIdx.x; e < eend; e += 1024) {
        int node = tgt[e];
        int r = atomicAdd(&lh[node], 1);   // LDS atomic — fast
        rank[e] = (unsigned short)r;       // coalesced
    }
    __syncthreads();
    int* row = hb + (size_t)blockIdx.x * N;
    for (int i = threadIdx.x; i < N; i += 1024) row[i] = lh[i];  // coalesced
}

__global__ void colsum_kernel(const int* __restrict__ hb, int* __restrict__ tot,
                              int nblk, int N) {
    int n = blockIdx.x * blockDim.x + threadIdx.x;
    if (n >= N) return;
    int s = 0;
    for (int b = 0; b < nblk; ++b) s += hb[(size_t)b * N + n];
    tot[n] = s;
}

__global__ __launch_bounds__(1024) void scan_kernel(const int* __restrict__ hist,
                                                    int* __restrict__ cursor, int N) {
    __shared__ int part[1024];
    int t = threadIdx.x;
    int per = (N + 1023) >> 10;
    int lo = t * per, hi = min(lo + per, N);
    int s = 0;
    for (int i = lo; i < hi; ++i) s += hist[i];
    part[t] = s;
    __syncthreads();
    for (int d = 1; d < 1024; d <<= 1) {
        int v = (t >= d) ? part[t - d] : 0;
        __syncthreads();
        part[t] += v;
        __syncthreads();
    }
    int off = (t == 0) ? 0 : part[t - 1];
    for (int i = lo; i < hi; ++i) { cursor[i] = off; off += hist[i]; }
}

__global__ void offsets_kernel(int* __restrict__ hb, const int* __restrict__ base,
                               int nblk, int N) {
    int n = blockIdx.x * blockDim.x + threadIdx.x;
    if (n >= N) return;
    int run = base[n];
    for (int b = 0; b < nblk; ++b) {
        size_t idx = (size_t)b * N + n;
        int c = hb[idx];
        hb[idx] = run;
        run += c;
    }
}

__global__ void emit_perm_kernel(const int* __restrict__ tgt,
                                 const unsigned short* __restrict__ rank,
                                 const int* __restrict__ hb,
                                 int* __restrict__ perm, int* __restrict__ snode,
                                 int E, int N) {
    int e = blockIdx.x * blockDim.x + threadIdx.x;
    if (e >= E) return;
    int node = tgt[e];
    int b = e >> CHUNK_LOG;
    int pos = hb[(size_t)b * N + node] + (int)rank[e];
    perm[pos] = e;
    snode[pos] = node;
}

// One wave owns 32 sorted-order edges end-to-end; residual X in fp32 regs.
// Matmuls transposed: D[feat][edge] via mfma_f32_32x32x16_bf16.
// C/D: edge=lane&31, feat=mb*32+(reg&3)+8*(reg>>2)+4*(lane>>5).
//
// Activations live ENTIRELY IN REGISTERS (cross-half exchange via
// __shfl_xor(.,32) + selects; verified r3/r4). Bias folded into MFMA C-init.
// Weights staged via global_load_lds into a double-buffered 2x32KB LDS.
//
// r5: 512-thread blocks (8 waves) SHARING the weight dbuf. LDS/block ~68KB
// -> still 2 blocks/CU, but 16 waves/CU = 4 waves/SIMD (was 2): doubles the
// latency-hiding for trans-op stalls / ds_bpermute / bias loads without
// adding any VALU work. VGPR cap at (512,4) is 128; r4 needed 124.
__global__ __launch_bounds__(512, 4) void fused_mlp_scatter(
    const float* __restrict__ m,
    const int* __restrict__ perm,
    const int* __restrict__ snode,
    const __bf16* __restrict__ wmats,
    const float* __restrict__ b1,
    const float* __restrict__ b2,
    const float* __restrict__ blin,
    float* __restrict__ out,
    int E, int ntiles)
{
    __shared__ __align__(16) char smem[69632];   // max(2x32KB wdbuf, epi overlay)
    float* ybuf = (float*)smem;                  // 8*32*68 f32 epilogue overlay

    const int tid  = threadIdx.x;
    const int w    = tid >> 6;
    const int lane = tid & 63;
    const int l31  = lane & 31;
    const int half = lane >> 5;

    const int tile    = blockIdx.x * 8 + w;
    const bool activeW = (tile < ntiles);
    const int pos = tile * 32 + l31;
    const bool evalid = activeW && (pos < E);

    int eidx = 0, mynode = 0;
    if (evalid) { eidx = perm[pos]; mynode = snode[pos]; }

    floatx4 X[4][4];
    floatx16 acc[4];
    int bw[8][4];   // B-fragments for current stage, fully static-indexed

    #define BUILD_BW(KS, VA0,VA1,VA2,VA3, VB0,VB1,VB2,VB3) do {              \
        int A0_ = pack2((VA0), (VA1)); int A1_ = pack2((VA2), (VA3));        \
        int B0_ = pack2((VB0), (VB1)); int B1_ = pack2((VB2), (VB3));        \
        int N0_ = half ? A0_ : B0_;  int N1_ = half ? A1_ : B1_;             \
        int S0_ = __shfl_xor(N0_, 32, 64);                                   \
        int S1_ = __shfl_xor(N1_, 32, 64);                                   \
        bw[KS][0] = half ? S0_ : A0_;  bw[KS][1] = half ? S1_ : A1_;         \
        bw[KS][2] = half ? B0_ : S0_;  bw[KS][3] = half ? B1_ : S1_;         \
    } while (0)

    // staging: 512 threads x 16B = 8KB per issue; 4 issues cover 32KB.
    // LDS dest decomposes as wave-uniform base (w*1024 + i*8192) + lane*16.
    // prologue: issue stage-0 weight loads into buffer 0
    #pragma unroll
    for (int i = 0; i < 4; ++i)
        gload_lds16((const char*)wmats + i * 8192 + tid * 16,
                    smem + i * 8192 + tid * 16);

    if (activeW) {
        const float* mrow = m + (size_t)eidx * HDIM;
        #pragma unroll
        for (int mb = 0; mb < 4; ++mb)
            #pragma unroll
            for (int q = 0; q < 4; ++q) {
                int f0 = mb * 32 + q * 8 + half * 4;
                X[mb][q] = *(const floatx4*)(mrow + f0);
            }
        // initial activations: silu(X) -> in-register B-fragments
        #pragma unroll
        for (int ks = 0; ks < 8; ++ks) {
            int mb = ks >> 1, qa = (ks & 1) * 2, qb = qa + 1;
            BUILD_BW(ks,
                silu_f(X[mb][qa][0]), silu_f(X[mb][qa][1]),
                silu_f(X[mb][qa][2]), silu_f(X[mb][qa][3]),
                silu_f(X[mb][qb][0]), silu_f(X[mb][qb][1]),
                silu_f(X[mb][qb][2]), silu_f(X[mb][qb][3]));
        }
    }

    #pragma unroll
    for (int s = 0; s < NSTAGE; ++s) {
        // barrier drains vmcnt -> buf[s&1] weights resident; all waves are
        // also done reading buf[(s&1)^1], so prefetching into it is race-free.
        __syncthreads();
        if (s < NSTAGE - 1) {
            const char* gsrc = (const char*)wmats + (((size_t)(s + 1)) << 15) + tid * 16;
            char* ldst = smem + (((s + 1) & 1) << 15) + tid * 16;
            #pragma unroll
            for (int i = 0; i < 4; ++i)
                gload_lds16(gsrc + i * 8192, ldst + i * 8192);
        }
        if (!activeW) continue;

        const __bf16* wl = (const __bf16*)(smem + ((s & 1) << 15));

        // acc C-init = bias for this stage (folds the bias add into MFMA)
        {
            const float* bias = (s == 6) ? blin
                              : ((s & 1) ? b2 + (s >> 1) * HDIM
                                         : b1 + (s >> 1) * HDIM);
            #pragma unroll
            for (int mb = 0; mb < 4; ++mb)
                #pragma unroll
                for (int q = 0; q < 4; ++q) {
                    floatx4 bv = *(const floatx4*)(bias + mb * 32 + q * 8 + half * 4);
                    #pragma unroll
                    for (int j = 0; j < 4; ++j) acc[mb][q * 4 + j] = bv[j];
                }
        }

        #pragma unroll
        for (int ks = 0; ks < 8; ++ks) {
            bf16x8 bfrag = frag_from(bw[ks][0], bw[ks][1], bw[ks][2], bw[ks][3]);
            int krow = ks * 2 + half;
            #pragma unroll
            for (int mb = 0; mb < 4; ++mb) {
                int mr = mb * 32 + l31;
                bf16x8 afrag = *(const bf16x8*)(&wl[(mr << 7) + ((krow ^ (mr & 7)) << 3)]);
                acc[mb] = __builtin_amdgcn_mfma_f32_32x32x16_bf16(afrag, bfrag, acc[mb], 0, 0, 0);
            }
        }

        if (s == 6) {
            // final silu IN-PLACE into acc (bias already included via C-init)
            #pragma unroll
            for (int mb = 0; mb < 4; ++mb)
                #pragma unroll
                for (int r = 0; r < 16; ++r)
                    acc[mb][r] = silu_f(acc[mb][r]);
        } else if ((s & 1) == 0) {
            // h = silu(acc); X unchanged; build next-stage B-fragments
            #pragma unroll
            for (int ks = 0; ks < 8; ++ks) {
                int mb = ks >> 1, qa = (ks & 1) * 2, qb = qa + 1;
                BUILD_BW(ks,
                    silu_f(acc[mb][qa * 4 + 0]), silu_f(acc[mb][qa * 4 + 1]),
                    silu_f(acc[mb][qa * 4 + 2]), silu_f(acc[mb][qa * 4 + 3]),
                    silu_f(acc[mb][qb * 4 + 0]), silu_f(acc[mb][qb * 4 + 1]),
                    silu_f(acc[mb][qb * 4 + 2]), silu_f(acc[mb][qb * 4 + 3]));
            }
        } else {
            // X += acc (residual); act = (s==5) ? X : silu(X)
            #pragma unroll
            for (int ks = 0; ks < 8; ++ks) {
                int mb = ks >> 1, qa = (ks & 1) * 2, qb = qa + 1;
                float va[4], vb[4];
                #pragma unroll
                for (int j = 0; j < 4; ++j) {
                    float nx = X[mb][qa][j] + acc[mb][qa * 4 + j];
                    X[mb][qa][j] = nx;
                    va[j] = (s == 5) ? nx : silu_f(nx);
                }
                #pragma unroll
                for (int j = 0; j < 4; ++j) {
                    float nx = X[mb][qb][j] + acc[mb][qb * 4 + j];
                    X[mb][qb][j] = nx;
                    vb[j] = (s == 5) ? nx : silu_f(nx);
                }
                BUILD_BW(ks, va[0], va[1], va[2], va[3],
                             vb[0], vb[1], vb[2], vb[3]);
            }
        }
    }

    // ---- epilogue: all waves done with weight LDS before ybuf overlay ----
    // Two 64-feat passes through a 8*32*68-float buffer (wave-private rows).
    __syncthreads();
    if (activeW) {
        const int ebase = tile * 32;
        const int cnt = min(32, E - ebase);
        float* yrow = ybuf + (w * 32 + l31) * 68;
        const float* yb = ybuf + w * 32 * 68;
        #pragma unroll
        for (int p = 0; p < 2; ++p) {
            #pragma unroll
            for (int mbh = 0; mbh < 2; ++mbh) {
                int mb = 2 * p + mbh;
                #pragma unroll
                for (int q = 0; q < 4; ++q) {
                    int f0 = mbh * 32 + q * 8 + half * 4;   // within-pass feat
                    floatx4 v;
                    for (int j = 0; j < 4; ++j) v[j] = acc[mb][q * 4 + j];
                    *(floatx4*)(yrow + f0) = v;
                }
            }
            // wave-private segmented accumulate + atomic row-writes
            int cur = __builtin_amdgcn_readlane(mynode, 0);
            float a0 = 0.f;
            for (int e = 0; e < cnt; ++e) {
                int node = __builtin_amdgcn_readlane(mynode, e);
                if (node != cur) {
                    unsafeAtomicAdd(out + (size_t)cur * HDIM + p * 64 + lane, a0);
                    cur = node; a0 = 0.f;
                }
                a0 += yb[e * 68 + lane];
            }
            unsafeAtomicAdd(out + (size_t)cur * HDIM + p * 64 + lane, a0);
        }
    }
    #undef BUILD_BW
}

extern "C" void kernel_launch(void* const* d_in, const int* in_sizes, int n_in,
                              void* d_out, int out_size, void* d_ws, size_t ws_size,
                              hipStream_t stream) {
    const float* m      = (const float*)d_in[0];
    const int* edge_idx = (const int*)d_in[1];
    const float* W1     = (const float*)d_in[3];
    const float* b1     = (const float*)d_in[4];
    const float* W2     = (const float*)d_in[5];
    const float* b2     = (const float*)d_in[6];
    const float* Wlin   = (const float*)d_in[7];
    const float* blin   = (const float*)d_in[8];

    int E = in_sizes[0] / HDIM;
    int N = out_size / HDIM;
    const int* tgt = edge_idx + E;

    int nblk = (E + CHUNK - 1) >> CHUNK_LOG;   // 8192-edge chunks (62 for E=500k)

    // workspace layout (256B-aligned)
    char* ws = (char*)d_ws;
    size_t off = 0;
    auto align_up = [](size_t v) { return (v + 255) & ~(size_t)255; };

    __bf16* wbf = (__bf16*)(ws + off);
    off = align_up(off + (size_t)NSTAGE * HDIM * HDIM * sizeof(__bf16));
    unsigned short* rank = (unsigned short*)(ws + off);
    off = align_up(off + (size_t)E * sizeof(unsigned short));
    int* hb = (int*)(ws + off);
    off = align_up(off + (size_t)nblk * N * sizeof(int));
    int* tot = (int*)(ws + off);
    off = align_up(off + (size_t)N * sizeof(int));
    int* base = (int*)(ws + off);
    off = align_up(off + (size_t)N * sizeof(int));
    int* perm = (int*)(ws + off);
    off = align_up(off + (size_t)E * sizeof(int));
    int* snode = (int*)(ws + off);
    off = align_up(off + (size_t)E * sizeof(int));

    hipMemsetAsync(d_out, 0, (size_t)out_size * sizeof(float), stream);

    convert_weights<<<(NSTAGE * HDIM * HDIM + 255) / 256, 256, 0, stream>>>(W1, W2, Wlin, wbf);

    // atomic-free counting sort
    hist_rank_kernel<<<nblk, 1024, 0, stream>>>(tgt, rank, hb, E, N);
    colsum_kernel<<<(N + 255) / 256, 256, 0, stream>>>(hb, tot, nblk, N);
    scan_kernel<<<1, 1024, 0, stream>>>(tot, base, N);
    offsets_kernel<<<(N + 255) / 256, 256, 0, stream>>>(hb, base, nblk, N);
    emit_perm_kernel<<<(E + 255) / 256, 256, 0, stream>>>(tgt, rank, hb, perm, snode, E, N);

    int ntiles  = (E + 31) / 32;
    int nblocks = (ntiles + 7) / 8;
    fused_mlp_scatter<<<nblocks, 512, 0, stream>>>(m, perm, snode, wbf, b1, b2, blin,
                                                   (float*)d_out, E, ntiles);
}

// Round 6
// 607.113 us; speedup vs baseline: 1.2415x; 1.2415x over previous
//
#include <hip/hip_runtime.h>
#include <hip/hip_bf16.h>

#define HDIM 128
#define NSTAGE 7
#define CHUNK_LOG 13
#define CHUNK (1 << CHUNK_LOG)

typedef __bf16 bf16x8 __attribute__((ext_vector_type(8)));
typedef __bf16 bf16x2 __attribute__((ext_vector_type(2)));
typedef float floatx16 __attribute__((ext_vector_type(16)));
typedef float floatx4 __attribute__((ext_vector_type(4)));
typedef int intx4 __attribute__((ext_vector_type(4)));

__device__ __forceinline__ float silu_f(float x) {
    return x * __builtin_amdgcn_rcpf(1.0f + __expf(-x));
}

__device__ __forceinline__ int pack2(float a, float b) {
    bf16x2 h;
    h[0] = (__bf16)a;
    h[1] = (__bf16)b;
    return __builtin_bit_cast(int, h);
}

__device__ __forceinline__ bf16x8 frag_from(int w0, int w1, int w2, int w3) {
    intx4 v; v[0] = w0; v[1] = w1; v[2] = w2; v[3] = w3;
    return __builtin_bit_cast(bf16x8, v);
}

// async global->LDS, 16B per lane; LDS dest = wave-uniform base + lane*16.
__device__ __forceinline__ void gload_lds16(const void* g, void* l) {
    __builtin_amdgcn_global_load_lds(
        (const __attribute__((address_space(1))) unsigned int*)g,
        (__attribute__((address_space(3))) unsigned int*)l, 16, 0, 0);
}

// Weights -> bf16. Stage order W1[0],W2[0],W1[1],W2[1],W1[2],W2[2],Wlin.
// NEW layout: per stage, two contiguous 16KB HALF-TILES (k<64 | k>=64), each
// [mrow][64] with the XOR swizzle applied within the half:
//   elem [s][mrow][k] -> s*16384 + (k>>6)*8192 + mrow*64
//                        + (( ((k>>3)&7) ^ (mrow&7) ) << 3) + (k&7)
__global__ void convert_weights(const float* __restrict__ W1,
                                const float* __restrict__ W2,
                                const float* __restrict__ Wlin,
                                __bf16* __restrict__ dst) {
    int idx = blockIdx.x * blockDim.x + threadIdx.x;
    if (idx >= NSTAGE * HDIM * HDIM) return;
    int s    = idx >> 14;
    int rem  = idx & 16383;
    int mrow = rem >> 7;
    int k    = rem & 127;
    const float* src;
    if (s == 6) src = Wlin;
    else {
        int l = s >> 1;
        src = ((s & 1) ? W2 : W1) + l * HDIM * HDIM;
    }
    float v = src[mrow * HDIM + k];
    int khalf = k >> 6;
    int c     = (k >> 3) & 7;
    int dsti  = (s << 14) + (khalf << 13) + (mrow << 6)
              + (((c ^ (mrow & 7)) << 3) | (k & 7));
    dst[dsti] = (__bf16)v;
}

// ---- atomic-free counting sort of edges by target node ----
__global__ __launch_bounds__(1024) void hist_rank_kernel(
    const int* __restrict__ tgt,
    unsigned short* __restrict__ rank,
    int* __restrict__ hb,
    int E, int N)
{
    __shared__ int lh[10240];   // N = 10000 for this problem
    for (int i = threadIdx.x; i < N; i += 1024) lh[i] = 0;
    __syncthreads();
    int ebase = blockIdx.x << CHUNK_LOG;
    int eend  = min(ebase + CHUNK, E);
    for (int e = ebase + (int)threadIdx.x; e < eend; e += 1024) {
        int node = tgt[e];
        int r = atomicAdd(&lh[node], 1);   // LDS atomic — fast
        rank[e] = (unsigned short)r;       // coalesced
    }
    __syncthreads();
    int* row = hb + (size_t)blockIdx.x * N;
    for (int i = threadIdx.x; i < N; i += 1024) row[i] = lh[i];  // coalesced
}

__global__ void colsum_kernel(const int* __restrict__ hb, int* __restrict__ tot,
                              int nblk, int N) {
    int n = blockIdx.x * blockDim.x + threadIdx.x;
    if (n >= N) return;
    int s = 0;
    for (int b = 0; b < nblk; ++b) s += hb[(size_t)b * N + n];
    tot[n] = s;
}

__global__ __launch_bounds__(1024) void scan_kernel(const int* __restrict__ hist,
                                                    int* __restrict__ cursor, int N) {
    __shared__ int part[1024];
    int t = threadIdx.x;
    int per = (N + 1023) >> 10;
    int lo = t * per, hi = min(lo + per, N);
    int s = 0;
    for (int i = lo; i < hi; ++i) s += hist[i];
    part[t] = s;
    __syncthreads();
    for (int d = 1; d < 1024; d <<= 1) {
        int v = (t >= d) ? part[t - d] : 0;
        __syncthreads();
        part[t] += v;
        __syncthreads();
    }
    int off = (t == 0) ? 0 : part[t - 1];
    for (int i = lo; i < hi; ++i) { cursor[i] = off; off += hist[i]; }
}

__global__ void offsets_kernel(int* __restrict__ hb, const int* __restrict__ base,
                               int nblk, int N) {
    int n = blockIdx.x * blockDim.x + threadIdx.x;
    if (n >= N) return;
    int run = base[n];
    for (int b = 0; b < nblk; ++b) {
        size_t idx = (size_t)b * N + n;
        int c = hb[idx];
        hb[idx] = run;
        run += c;
    }
}

__global__ void emit_perm_kernel(const int* __restrict__ tgt,
                                 const unsigned short* __restrict__ rank,
                                 const int* __restrict__ hb,
                                 int* __restrict__ perm, int* __restrict__ snode,
                                 int E, int N) {
    int e = blockIdx.x * blockDim.x + threadIdx.x;
    if (e >= E) return;
    int node = tgt[e];
    int b = e >> CHUNK_LOG;
    int pos = hb[(size_t)b * N + node] + (int)rank[e];
    perm[pos] = e;
    snode[pos] = node;
}

// One wave owns 32 sorted-order edges end-to-end; residual X in fp32 regs.
// Matmuls transposed: D[feat][edge] via mfma_f32_32x32x16_bf16.
// C/D: edge=lane&31, feat=mb*32+(reg&3)+8*(reg>>2)+4*(lane>>5).
//
// Activations live ENTIRELY IN REGISTERS (cross-half exchange via
// __shfl_xor(.,32) + selects; verified r3/r4). Bias folded into MFMA C-init
// (loads hoisted before the half-A barrier so they drain during the wait).
//
// r6: HALF-STAGE weight staging. Each stage = two 16KB half-tiles (k<64 in
// buf0, k>=64 in buf1; 2x16KB ping-pong). One barrier per half; prefetch of
// half h+1 issued right after the barrier that freed its buffer (readers of
// that buffer were half h-1, done before this barrier). LDS = max(32KB,
// 34816B epilogue overlay) -> 3 blocks/CU at (256,3): 3 waves/SIMD (was 2),
// VGPR cap 170 comfortably above the ~124 this kernel needs (r5's 128-cap
// spill disaster avoided).
__global__ __launch_bounds__(256, 3) void fused_mlp_scatter(
    const float* __restrict__ m,
    const int* __restrict__ perm,
    const int* __restrict__ snode,
    const __bf16* __restrict__ wmats,
    const float* __restrict__ b1,
    const float* __restrict__ b2,
    const float* __restrict__ blin,
    float* __restrict__ out,
    int E, int ntiles)
{
    __shared__ __align__(16) char smem[34816];   // 2x16KB wbuf | epi overlay
    float* ybuf = (float*)smem;                  // 4*32*68 f32 epilogue overlay

    const int tid  = threadIdx.x;
    const int w    = tid >> 6;
    const int lane = tid & 63;
    const int l31  = lane & 31;
    const int half = lane >> 5;

    const int tile    = blockIdx.x * 4 + w;
    const bool activeW = (tile < ntiles);
    const int pos = tile * 32 + l31;
    const bool evalid = activeW && (pos < E);

    int eidx = 0, mynode = 0;
    if (evalid) { eidx = perm[pos]; mynode = snode[pos]; }

    floatx4 X[4][4];
    floatx16 acc[4];
    int bw[8][4];   // B-fragments for current stage, fully static-indexed

    #define BUILD_BW(KS, VA0,VA1,VA2,VA3, VB0,VB1,VB2,VB3) do {              \
        int A0_ = pack2((VA0), (VA1)); int A1_ = pack2((VA2), (VA3));        \
        int B0_ = pack2((VB0), (VB1)); int B1_ = pack2((VB2), (VB3));        \
        int N0_ = half ? A0_ : B0_;  int N1_ = half ? A1_ : B1_;             \
        int S0_ = __shfl_xor(N0_, 32, 64);                                   \
        int S1_ = __shfl_xor(N1_, 32, 64);                                   \
        bw[KS][0] = half ? S0_ : A0_;  bw[KS][1] = half ? S1_ : A1_;         \
        bw[KS][2] = half ? B0_ : S0_;  bw[KS][3] = half ? B1_ : S1_;         \
    } while (0)

    // stage one 16KB half-tile (hs = 0..13) into buf (0 or 1).
    // 256 threads x 16B = 4KB/issue; 4 issues. Dest = uniform base + lane*16.
    #define STAGE_HALF(HS, BUF) do {                                         \
        const char* g_ = (const char*)wmats + ((HS) << 14) + tid * 16;       \
        char* l_ = smem + ((BUF) << 14) + tid * 16;                          \
        _Pragma("unroll")                                                    \
        for (int i_ = 0; i_ < 4; ++i_)                                       \
            gload_lds16(g_ + i_ * 4096, l_ + i_ * 4096);                     \
    } while (0)

    // prologue: issue stage-0 half-A into buf0
    STAGE_HALF(0, 0);

    if (activeW) {
        const float* mrow = m + (size_t)eidx * HDIM;
        #pragma unroll
        for (int mb = 0; mb < 4; ++mb)
            #pragma unroll
            for (int q = 0; q < 4; ++q) {
                int f0 = mb * 32 + q * 8 + half * 4;
                X[mb][q] = *(const floatx4*)(mrow + f0);
            }
        // initial activations: silu(X) -> in-register B-fragments
        #pragma unroll
        for (int ks = 0; ks < 8; ++ks) {
            int mb = ks >> 1, qa = (ks & 1) * 2, qb = qa + 1;
            BUILD_BW(ks,
                silu_f(X[mb][qa][0]), silu_f(X[mb][qa][1]),
                silu_f(X[mb][qa][2]), silu_f(X[mb][qa][3]),
                silu_f(X[mb][qb][0]), silu_f(X[mb][qb][1]),
                silu_f(X[mb][qb][2]), silu_f(X[mb][qb][3]));
        }
    }

    #pragma unroll
    for (int s = 0; s < NSTAGE; ++s) {
        // bias C-init BEFORE the barrier: loads drain during the barrier wait
        if (activeW) {
            const float* bias = (s == 6) ? blin
                              : ((s & 1) ? b2 + (s >> 1) * HDIM
                                         : b1 + (s >> 1) * HDIM);
            #pragma unroll
            for (int mb = 0; mb < 4; ++mb)
                #pragma unroll
                for (int q = 0; q < 4; ++q) {
                    floatx4 bv = *(const floatx4*)(bias + mb * 32 + q * 8 + half * 4);
                    #pragma unroll
                    for (int j = 0; j < 4; ++j) acc[mb][q * 4 + j] = bv[j];
                }
        }

        // ---- half A (k<64, buf0) ----
        __syncthreads();                 // buf0 resident; buf1 readers done
        STAGE_HALF(2 * s + 1, 1);        // prefetch half-B
        if (activeW) {
            const __bf16* wl = (const __bf16*)smem;
            #pragma unroll
            for (int lks = 0; lks < 4; ++lks) {
                bf16x8 bfrag = frag_from(bw[lks][0], bw[lks][1], bw[lks][2], bw[lks][3]);
                int krl = lks * 2 + half;
                #pragma unroll
                for (int mb = 0; mb < 4; ++mb) {
                    int mr = mb * 32 + l31;
                    bf16x8 afrag = *(const bf16x8*)(&wl[(mr << 6) + ((krl ^ (mr & 7)) << 3)]);
                    acc[mb] = __builtin_amdgcn_mfma_f32_32x32x16_bf16(afrag, bfrag, acc[mb], 0, 0, 0);
                }
            }
        }

        // ---- half B (k>=64, buf1) ----
        __syncthreads();                 // buf1 resident; buf0 readers done
        if (s < NSTAGE - 1) STAGE_HALF(2 * s + 2, 0);   // prefetch next half-A
        if (!activeW) continue;
        {
            const __bf16* wl = (const __bf16*)(smem + 16384);
            #pragma unroll
            for (int lks = 0; lks < 4; ++lks) {
                bf16x8 bfrag = frag_from(bw[4 + lks][0], bw[4 + lks][1],
                                         bw[4 + lks][2], bw[4 + lks][3]);
                int krl = lks * 2 + half;
                #pragma unroll
                for (int mb = 0; mb < 4; ++mb) {
                    int mr = mb * 32 + l31;
                    bf16x8 afrag = *(const bf16x8*)(&wl[(mr << 6) + ((krl ^ (mr & 7)) << 3)]);
                    acc[mb] = __builtin_amdgcn_mfma_f32_32x32x16_bf16(afrag, bfrag, acc[mb], 0, 0, 0);
                }
            }
        }

        if (s == 6) {
            // final silu IN-PLACE into acc (bias already included via C-init)
            #pragma unroll
            for (int mb = 0; mb < 4; ++mb)
                #pragma unroll
                for (int r = 0; r < 16; ++r)
                    acc[mb][r] = silu_f(acc[mb][r]);
        } else if ((s & 1) == 0) {
            // h = silu(acc); X unchanged; build next-stage B-fragments
            #pragma unroll
            for (int ks = 0; ks < 8; ++ks) {
                int mb = ks >> 1, qa = (ks & 1) * 2, qb = qa + 1;
                BUILD_BW(ks,
                    silu_f(acc[mb][qa * 4 + 0]), silu_f(acc[mb][qa * 4 + 1]),
                    silu_f(acc[mb][qa * 4 + 2]), silu_f(acc[mb][qa * 4 + 3]),
                    silu_f(acc[mb][qb * 4 + 0]), silu_f(acc[mb][qb * 4 + 1]),
                    silu_f(acc[mb][qb * 4 + 2]), silu_f(acc[mb][qb * 4 + 3]));
            }
        } else {
            // X += acc (residual); act = (s==5) ? X : silu(X)
            #pragma unroll
            for (int ks = 0; ks < 8; ++ks) {
                int mb = ks >> 1, qa = (ks & 1) * 2, qb = qa + 1;
                float va[4], vb[4];
                #pragma unroll
                for (int j = 0; j < 4; ++j) {
                    float nx = X[mb][qa][j] + acc[mb][qa * 4 + j];
                    X[mb][qa][j] = nx;
                    va[j] = (s == 5) ? nx : silu_f(nx);
                }
                #pragma unroll
                for (int j = 0; j < 4; ++j) {
                    float nx = X[mb][qb][j] + acc[mb][qb * 4 + j];
                    X[mb][qb][j] = nx;
                    vb[j] = (s == 5) ? nx : silu_f(nx);
                }
                BUILD_BW(ks, va[0], va[1], va[2], va[3],
                             vb[0], vb[1], vb[2], vb[3]);
            }
        }
    }

    // ---- epilogue: all waves done with weight LDS before ybuf overlay ----
    // Two 64-feat passes through a 4*32*68-float buffer (wave-private rows).
    __syncthreads();
    if (activeW) {
        const int ebase = tile * 32;
        const int cnt = min(32, E - ebase);
        float* yrow = ybuf + (w * 32 + l31) * 68;
        const float* yb = ybuf + w * 32 * 68;
        #pragma unroll
        for (int p = 0; p < 2; ++p) {
            #pragma unroll
            for (int mbh = 0; mbh < 2; ++mbh) {
                int mb = 2 * p + mbh;
                #pragma unroll
                for (int q = 0; q < 4; ++q) {
                    int f0 = mbh * 32 + q * 8 + half * 4;   // within-pass feat
                    floatx4 v;
                    for (int j = 0; j < 4; ++j) v[j] = acc[mb][q * 4 + j];
                    *(floatx4*)(yrow + f0) = v;
                }
            }
            // wave-private segmented accumulate + atomic row-writes
            int cur = __builtin_amdgcn_readlane(mynode, 0);
            float a0 = 0.f;
            for (int e = 0; e < cnt; ++e) {
                int node = __builtin_amdgcn_readlane(mynode, e);
                if (node != cur) {
                    unsafeAtomicAdd(out + (size_t)cur * HDIM + p * 64 + lane, a0);
                    cur = node; a0 = 0.f;
                }
                a0 += yb[e * 68 + lane];
            }
            unsafeAtomicAdd(out + (size_t)cur * HDIM + p * 64 + lane, a0);
        }
    }
    #undef BUILD_BW
    #undef STAGE_HALF
}

extern "C" void kernel_launch(void* const* d_in, const int* in_sizes, int n_in,
                              void* d_out, int out_size, void* d_ws, size_t ws_size,
                              hipStream_t stream) {
    const float* m      = (const float*)d_in[0];
    const int* edge_idx = (const int*)d_in[1];
    const float* W1     = (const float*)d_in[3];
    const float* b1     = (const float*)d_in[4];
    const float* W2     = (const float*)d_in[5];
    const float* b2     = (const float*)d_in[6];
    const float* Wlin   = (const float*)d_in[7];
    const float* blin   = (const float*)d_in[8];

    int E = in_sizes[0] / HDIM;
    int N = out_size / HDIM;
    const int* tgt = edge_idx + E;

    int nblk = (E + CHUNK - 1) >> CHUNK_LOG;   // 8192-edge chunks (62 for E=500k)

    // workspace layout (256B-aligned)
    char* ws = (char*)d_ws;
    size_t off = 0;
    auto align_up = [](size_t v) { return (v + 255) & ~(size_t)255; };

    __bf16* wbf = (__bf16*)(ws + off);
    off = align_up(off + (size_t)NSTAGE * HDIM * HDIM * sizeof(__bf16));
    unsigned short* rank = (unsigned short*)(ws + off);
    off = align_up(off + (size_t)E * sizeof(unsigned short));
    int* hb = (int*)(ws + off);
    off = align_up(off + (size_t)nblk * N * sizeof(int));
    int* tot = (int*)(ws + off);
    off = align_up(off + (size_t)N * sizeof(int));
    int* base = (int*)(ws + off);
    off = align_up(off + (size_t)N * sizeof(int));
    int* perm = (int*)(ws + off);
    off = align_up(off + (size_t)E * sizeof(int));
    int* snode = (int*)(ws + off);
    off = align_up(off + (size_t)E * sizeof(int));

    hipMemsetAsync(d_out, 0, (size_t)out_size * sizeof(float), stream);

    convert_weights<<<(NSTAGE * HDIM * HDIM + 255) / 256, 256, 0, stream>>>(W1, W2, Wlin, wbf);

    // atomic-free counting sort
    hist_rank_kernel<<<nblk, 1024, 0, stream>>>(tgt, rank, hb, E, N);
    colsum_kernel<<<(N + 255) / 256, 256, 0, stream>>>(hb, tot, nblk, N);
    scan_kernel<<<1, 1024, 0, stream>>>(tot, base, N);
    offsets_kernel<<<(N + 255) / 256, 256, 0, stream>>>(hb, base, nblk, N);
    emit_perm_kernel<<<(E + 255) / 256, 256, 0, stream>>>(tgt, rank, hb, perm, snode, E, N);

    int ntiles  = (E + 31) / 32;
    int nblocks = (ntiles + 3) / 4;
    fused_mlp_scatter<<<nblocks, 256, 0, stream>>>(m, perm, snode, wbf, b1, b2, blin,
                                                   (float*)d_out, E, ntiles);
}

// Round 7
// 571.109 us; speedup vs baseline: 1.3198x; 1.0630x over previous
//
#include <hip/hip_runtime.h>
#include <hip/hip_bf16.h>

#define HDIM 128
#define NSTAGE 7
#define CHUNK_LOG 13
#define CHUNK (1 << CHUNK_LOG)

typedef __bf16 bf16x8 __attribute__((ext_vector_type(8)));
typedef __bf16 bf16x2 __attribute__((ext_vector_type(2)));
typedef float floatx16 __attribute__((ext_vector_type(16)));
typedef float floatx4 __attribute__((ext_vector_type(4)));
typedef int intx4 __attribute__((ext_vector_type(4)));

__device__ __forceinline__ float silu_f(float x) {
    return x * __builtin_amdgcn_rcpf(1.0f + __expf(-x));
}

__device__ __forceinline__ int pack2(float a, float b) {
    bf16x2 h;
    h[0] = (__bf16)a;
    h[1] = (__bf16)b;
    return __builtin_bit_cast(int, h);
}

__device__ __forceinline__ void unpack2f(int p, float& x0, float& x1) {
    bf16x2 h = __builtin_bit_cast(bf16x2, p);
    x0 = (float)h[0];
    x1 = (float)h[1];
}

__device__ __forceinline__ bf16x8 frag_from(int w0, int w1, int w2, int w3) {
    intx4 v; v[0] = w0; v[1] = w1; v[2] = w2; v[3] = w3;
    return __builtin_bit_cast(bf16x8, v);
}

// async global->LDS, 16B per lane; LDS dest = wave-uniform base + lane*16.
__device__ __forceinline__ void gload_lds16(const void* g, void* l) {
    __builtin_amdgcn_global_load_lds(
        (const __attribute__((address_space(1))) unsigned int*)g,
        (__attribute__((address_space(3))) unsigned int*)l, 16, 0, 0);
}

// Weights -> bf16. Stage order W1[0],W2[0],W1[1],W2[1],W1[2],W2[2],Wlin.
// Per stage, two contiguous 16KB HALF-TILES (k<64 | k>=64), each [mrow][64]
// with the XOR swizzle applied within the half:
//   elem [s][mrow][k] -> s*16384 + (k>>6)*8192 + mrow*64
//                        + (( ((k>>3)&7) ^ (mrow&7) ) << 3) + (k&7)
__global__ void convert_weights(const float* __restrict__ W1,
                                const float* __restrict__ W2,
                                const float* __restrict__ Wlin,
                                __bf16* __restrict__ dst) {
    int idx = blockIdx.x * blockDim.x + threadIdx.x;
    if (idx >= NSTAGE * HDIM * HDIM) return;
    int s    = idx >> 14;
    int rem  = idx & 16383;
    int mrow = rem >> 7;
    int k    = rem & 127;
    const float* src;
    if (s == 6) src = Wlin;
    else {
        int l = s >> 1;
        src = ((s & 1) ? W2 : W1) + l * HDIM * HDIM;
    }
    float v = src[mrow * HDIM + k];
    int khalf = k >> 6;
    int c     = (k >> 3) & 7;
    int dsti  = (s << 14) + (khalf << 13) + (mrow << 6)
              + (((c ^ (mrow & 7)) << 3) | (k & 7));
    dst[dsti] = (__bf16)v;
}

// ---- atomic-free counting sort of edges by target node ----
__global__ __launch_bounds__(1024) void hist_rank_kernel(
    const int* __restrict__ tgt,
    unsigned short* __restrict__ rank,
    int* __restrict__ hb,
    int E, int N)
{
    __shared__ int lh[10240];   // N = 10000 for this problem
    for (int i = threadIdx.x; i < N; i += 1024) lh[i] = 0;
    __syncthreads();
    int ebase = blockIdx.x << CHUNK_LOG;
    int eend  = min(ebase + CHUNK, E);
    for (int e = ebase + (int)threadIdx.x; e < eend; e += 1024) {
        int node = tgt[e];
        int r = atomicAdd(&lh[node], 1);   // LDS atomic — fast
        rank[e] = (unsigned short)r;       // coalesced
    }
    __syncthreads();
    int* row = hb + (size_t)blockIdx.x * N;
    for (int i = threadIdx.x; i < N; i += 1024) row[i] = lh[i];  // coalesced
}

__global__ void colsum_kernel(const int* __restrict__ hb, int* __restrict__ tot,
                              int nblk, int N) {
    int n = blockIdx.x * blockDim.x + threadIdx.x;
    if (n >= N) return;
    int s = 0;
    for (int b = 0; b < nblk; ++b) s += hb[(size_t)b * N + n];
    tot[n] = s;
}

__global__ __launch_bounds__(1024) void scan_kernel(const int* __restrict__ hist,
                                                    int* __restrict__ cursor, int N) {
    __shared__ int part[1024];
    int t = threadIdx.x;
    int per = (N + 1023) >> 10;
    int lo = t * per, hi = min(lo + per, N);
    int s = 0;
    for (int i = lo; i < hi; ++i) s += hist[i];
    part[t] = s;
    __syncthreads();
    for (int d = 1; d < 1024; d <<= 1) {
        int v = (t >= d) ? part[t - d] : 0;
        __syncthreads();
        part[t] += v;
        __syncthreads();
    }
    int off = (t == 0) ? 0 : part[t - 1];
    for (int i = lo; i < hi; ++i) { cursor[i] = off; off += hist[i]; }
}

__global__ void offsets_kernel(int* __restrict__ hb, const int* __restrict__ base,
                               int nblk, int N) {
    int n = blockIdx.x * blockDim.x + threadIdx.x;
    if (n >= N) return;
    int run = base[n];
    for (int b = 0; b < nblk; ++b) {
        size_t idx = (size_t)b * N + n;
        int c = hb[idx];
        hb[idx] = run;
        run += c;
    }
}

__global__ void emit_perm_kernel(const int* __restrict__ tgt,
                                 const unsigned short* __restrict__ rank,
                                 const int* __restrict__ hb,
                                 int* __restrict__ perm, int* __restrict__ snode,
                                 int E, int N) {
    int e = blockIdx.x * blockDim.x + threadIdx.x;
    if (e >= E) return;
    int node = tgt[e];
    int b = e >> CHUNK_LOG;
    int pos = hb[(size_t)b * N + node] + (int)rank[e];
    perm[pos] = e;
    snode[pos] = node;
}

// One wave owns 32 sorted-order edges end-to-end.
// Matmuls transposed: D[feat][edge] via mfma_f32_32x32x16_bf16.
// C/D: edge=lane&31, feat=mb*32+(reg&3)+8*(reg>>2)+4*(lane>>5).
//
// Activations live ENTIRELY IN REGISTERS (cross-half exchange via
// __shfl_xor(.,32) + selects; verified r3/r4). Bias folded into MFMA C-init.
// Half-stage weight staging: 16KB half-tiles ping-ponged through 2x16KB LDS
// via global_load_lds; one barrier per half (verified r6).
//
// r7: residual X stored as PACKED BF16 (int Xp[4][4][2] = 32 VGPRs, was 64
// fp32). Register accounting (r3/r5/r6 spill post-mortems): unified demand
// was X(64)+bw(32)+misc(~28)+acc(64 AGPR) = ~188 -> spilled at every cap
// below 256. Now ~156 <= 170 cap of (256,3): 3 blocks/CU SPILL-FREE.
// Cost: bf16 rounding of the residual stream (unpack->add->repack at odd
// stages); MFMA inputs were bf16 already.
__global__ __launch_bounds__(256, 3) void fused_mlp_scatter(
    const float* __restrict__ m,
    const int* __restrict__ perm,
    const int* __restrict__ snode,
    const __bf16* __restrict__ wmats,
    const float* __restrict__ b1,
    const float* __restrict__ b2,
    const float* __restrict__ blin,
    float* __restrict__ out,
    int E, int ntiles)
{
    __shared__ __align__(16) char smem[34816];   // 2x16KB wbuf | epi overlay
    float* ybuf = (float*)smem;                  // 4*32*68 f32 epilogue overlay

    const int tid  = threadIdx.x;
    const int w    = tid >> 6;
    const int lane = tid & 63;
    const int l31  = lane & 31;
    const int half = lane >> 5;

    const int tile    = blockIdx.x * 4 + w;
    const bool activeW = (tile < ntiles);
    const int pos = tile * 32 + l31;
    const bool evalid = activeW && (pos < E);

    int eidx = 0, mynode = 0;
    if (evalid) { eidx = perm[pos]; mynode = snode[pos]; }

    int Xp[4][4][2];   // residual X, packed bf16 (2 feats per int)
    floatx16 acc[4];
    int bw[8][4];      // B-fragments for current stage, fully static-indexed

    #define BUILD_BW(KS, VA0,VA1,VA2,VA3, VB0,VB1,VB2,VB3) do {              \
        int A0_ = pack2((VA0), (VA1)); int A1_ = pack2((VA2), (VA3));        \
        int B0_ = pack2((VB0), (VB1)); int B1_ = pack2((VB2), (VB3));        \
        int N0_ = half ? A0_ : B0_;  int N1_ = half ? A1_ : B1_;             \
        int S0_ = __shfl_xor(N0_, 32, 64);                                   \
        int S1_ = __shfl_xor(N1_, 32, 64);                                   \
        bw[KS][0] = half ? S0_ : A0_;  bw[KS][1] = half ? S1_ : A1_;         \
        bw[KS][2] = half ? B0_ : S0_;  bw[KS][3] = half ? B1_ : S1_;         \
    } while (0)

    // stage one 16KB half-tile (hs = 0..13) into buf (0 or 1).
    // 256 threads x 16B = 4KB/issue; 4 issues. Dest = uniform base + lane*16.
    #define STAGE_HALF(HS, BUF) do {                                         \
        const char* g_ = (const char*)wmats + ((HS) << 14) + tid * 16;       \
        char* l_ = smem + ((BUF) << 14) + tid * 16;                          \
        _Pragma("unroll")                                                    \
        for (int i_ = 0; i_ < 4; ++i_)                                       \
            gload_lds16(g_ + i_ * 4096, l_ + i_ * 4096);                     \
    } while (0)

    // prologue: issue stage-0 half-A into buf0
    STAGE_HALF(0, 0);

    if (activeW) {
        const float* mrow = m + (size_t)eidx * HDIM;
        // per-mb: load 16 f32, pack into Xp, build the 2 B-fragment groups.
        // (keeps prologue transient pressure to ~16 regs instead of 64)
        #pragma unroll
        for (int mb = 0; mb < 4; ++mb) {
            floatx4 xv[4];
            #pragma unroll
            for (int q = 0; q < 4; ++q)
                xv[q] = *(const floatx4*)(mrow + mb * 32 + q * 8 + half * 4);
            #pragma unroll
            for (int q = 0; q < 4; ++q) {
                Xp[mb][q][0] = pack2(xv[q][0], xv[q][1]);
                Xp[mb][q][1] = pack2(xv[q][2], xv[q][3]);
            }
            BUILD_BW(2 * mb,
                silu_f(xv[0][0]), silu_f(xv[0][1]), silu_f(xv[0][2]), silu_f(xv[0][3]),
                silu_f(xv[1][0]), silu_f(xv[1][1]), silu_f(xv[1][2]), silu_f(xv[1][3]));
            BUILD_BW(2 * mb + 1,
                silu_f(xv[2][0]), silu_f(xv[2][1]), silu_f(xv[2][2]), silu_f(xv[2][3]),
                silu_f(xv[3][0]), silu_f(xv[3][1]), silu_f(xv[3][2]), silu_f(xv[3][3]));
        }
    }

    #pragma unroll
    for (int s = 0; s < NSTAGE; ++s) {
        // ---- half A (k<64, buf0) ----
        __syncthreads();                 // buf0 resident; buf1 readers done
        STAGE_HALF(2 * s + 1, 1);        // prefetch half-B
        if (activeW) {
            // acc C-init = bias (folds the bias add into MFMA)
            const float* bias = (s == 6) ? blin
                              : ((s & 1) ? b2 + (s >> 1) * HDIM
                                         : b1 + (s >> 1) * HDIM);
            #pragma unroll
            for (int mb = 0; mb < 4; ++mb)
                #pragma unroll
                for (int q = 0; q < 4; ++q) {
                    floatx4 bv = *(const floatx4*)(bias + mb * 32 + q * 8 + half * 4);
                    #pragma unroll
                    for (int j = 0; j < 4; ++j) acc[mb][q * 4 + j] = bv[j];
                }
            const __bf16* wl = (const __bf16*)smem;
            #pragma unroll
            for (int lks = 0; lks < 4; ++lks) {
                bf16x8 bfrag = frag_from(bw[lks][0], bw[lks][1], bw[lks][2], bw[lks][3]);
                int krl = lks * 2 + half;
                #pragma unroll
                for (int mb = 0; mb < 4; ++mb) {
                    int mr = mb * 32 + l31;
                    bf16x8 afrag = *(const bf16x8*)(&wl[(mr << 6) + ((krl ^ (mr & 7)) << 3)]);
                    acc[mb] = __builtin_amdgcn_mfma_f32_32x32x16_bf16(afrag, bfrag, acc[mb], 0, 0, 0);
                }
            }
        }

        // ---- half B (k>=64, buf1) ----
        __syncthreads();                 // buf1 resident; buf0 readers done
        if (s < NSTAGE - 1) STAGE_HALF(2 * s + 2, 0);   // prefetch next half-A
        if (!activeW) continue;
        {
            const __bf16* wl = (const __bf16*)(smem + 16384);
            #pragma unroll
            for (int lks = 0; lks < 4; ++lks) {
                bf16x8 bfrag = frag_from(bw[4 + lks][0], bw[4 + lks][1],
                                         bw[4 + lks][2], bw[4 + lks][3]);
                int krl = lks * 2 + half;
                #pragma unroll
                for (int mb = 0; mb < 4; ++mb) {
                    int mr = mb * 32 + l31;
                    bf16x8 afrag = *(const bf16x8*)(&wl[(mr << 6) + ((krl ^ (mr & 7)) << 3)]);
                    acc[mb] = __builtin_amdgcn_mfma_f32_32x32x16_bf16(afrag, bfrag, acc[mb], 0, 0, 0);
                }
            }
        }

        if (s == 6) {
            // final silu IN-PLACE into acc (bias already included via C-init)
            #pragma unroll
            for (int mb = 0; mb < 4; ++mb)
                #pragma unroll
                for (int r = 0; r < 16; ++r)
                    acc[mb][r] = silu_f(acc[mb][r]);
        } else if ((s & 1) == 0) {
            // h = silu(acc); X unchanged; build next-stage B-fragments
            #pragma unroll
            for (int ks = 0; ks < 8; ++ks) {
                int mb = ks >> 1, qa = (ks & 1) * 2, qb = qa + 1;
                BUILD_BW(ks,
                    silu_f(acc[mb][qa * 4 + 0]), silu_f(acc[mb][qa * 4 + 1]),
                    silu_f(acc[mb][qa * 4 + 2]), silu_f(acc[mb][qa * 4 + 3]),
                    silu_f(acc[mb][qb * 4 + 0]), silu_f(acc[mb][qb * 4 + 1]),
                    silu_f(acc[mb][qb * 4 + 2]), silu_f(acc[mb][qb * 4 + 3]));
            }
        } else {
            // X += acc (residual, bf16-packed); act = (s==5) ? X : silu(X)
            #pragma unroll
            for (int ks = 0; ks < 8; ++ks) {
                int mb = ks >> 1, qa = (ks & 1) * 2, qb = qa + 1;
                float va[4], vb[4];
                {
                    float x0, x1, x2, x3;
                    unpack2f(Xp[mb][qa][0], x0, x1);
                    unpack2f(Xp[mb][qa][1], x2, x3);
                    x0 += acc[mb][qa * 4 + 0]; x1 += acc[mb][qa * 4 + 1];
                    x2 += acc[mb][qa * 4 + 2]; x3 += acc[mb][qa * 4 + 3];
                    Xp[mb][qa][0] = pack2(x0, x1);
                    Xp[mb][qa][1] = pack2(x2, x3);
                    va[0] = (s == 5) ? x0 : silu_f(x0);
                    va[1] = (s == 5) ? x1 : silu_f(x1);
                    va[2] = (s == 5) ? x2 : silu_f(x2);
                    va[3] = (s == 5) ? x3 : silu_f(x3);
                }
                {
                    float x0, x1, x2, x3;
                    unpack2f(Xp[mb][qb][0], x0, x1);
                    unpack2f(Xp[mb][qb][1], x2, x3);
                    x0 += acc[mb][qb * 4 + 0]; x1 += acc[mb][qb * 4 + 1];
                    x2 += acc[mb][qb * 4 + 2]; x3 += acc[mb][qb * 4 + 3];
                    Xp[mb][qb][0] = pack2(x0, x1);
                    Xp[mb][qb][1] = pack2(x2, x3);
                    vb[0] = (s == 5) ? x0 : silu_f(x0);
                    vb[1] = (s == 5) ? x1 : silu_f(x1);
                    vb[2] = (s == 5) ? x2 : silu_f(x2);
                    vb[3] = (s == 5) ? x3 : silu_f(x3);
                }
                BUILD_BW(ks, va[0], va[1], va[2], va[3],
                             vb[0], vb[1], vb[2], vb[3]);
            }
        }
    }

    // ---- epilogue: all waves done with weight LDS before ybuf overlay ----
    // Two 64-feat passes through a 4*32*68-float buffer (wave-private rows).
    __syncthreads();
    if (activeW) {
        const int ebase = tile * 32;
        const int cnt = min(32, E - ebase);
        float* yrow = ybuf + (w * 32 + l31) * 68;
        const float* yb = ybuf + w * 32 * 68;
        #pragma unroll
        for (int p = 0; p < 2; ++p) {
            #pragma unroll
            for (int mbh = 0; mbh < 2; ++mbh) {
                int mb = 2 * p + mbh;
                #pragma unroll
                for (int q = 0; q < 4; ++q) {
                    int f0 = mbh * 32 + q * 8 + half * 4;   // within-pass feat
                    floatx4 v;
                    for (int j = 0; j < 4; ++j) v[j] = acc[mb][q * 4 + j];
                    *(floatx4*)(yrow + f0) = v;
                }
            }
            // wave-private segmented accumulate + atomic row-writes
            int cur = __builtin_amdgcn_readlane(mynode, 0);
            float a0 = 0.f;
            for (int e = 0; e < cnt; ++e) {
                int node = __builtin_amdgcn_readlane(mynode, e);
                if (node != cur) {
                    unsafeAtomicAdd(out + (size_t)cur * HDIM + p * 64 + lane, a0);
                    cur = node; a0 = 0.f;
                }
                a0 += yb[e * 68 + lane];
            }
            unsafeAtomicAdd(out + (size_t)cur * HDIM + p * 64 + lane, a0);
        }
    }
    #undef BUILD_BW
    #undef STAGE_HALF
}

extern "C" void kernel_launch(void* const* d_in, const int* in_sizes, int n_in,
                              void* d_out, int out_size, void* d_ws, size_t ws_size,
                              hipStream_t stream) {
    const float* m      = (const float*)d_in[0];
    const int* edge_idx = (const int*)d_in[1];
    const float* W1     = (const float*)d_in[3];
    const float* b1     = (const float*)d_in[4];
    const float* W2     = (const float*)d_in[5];
    const float* b2     = (const float*)d_in[6];
    const float* Wlin   = (const float*)d_in[7];
    const float* blin   = (const float*)d_in[8];

    int E = in_sizes[0] / HDIM;
    int N = out_size / HDIM;
    const int* tgt = edge_idx + E;

    int nblk = (E + CHUNK - 1) >> CHUNK_LOG;   // 8192-edge chunks (62 for E=500k)

    // workspace layout (256B-aligned)
    char* ws = (char*)d_ws;
    size_t off = 0;
    auto align_up = [](size_t v) { return (v + 255) & ~(size_t)255; };

    __bf16* wbf = (__bf16*)(ws + off);
    off = align_up(off + (size_t)NSTAGE * HDIM * HDIM * sizeof(__bf16));
    unsigned short* rank = (unsigned short*)(ws + off);
    off = align_up(off + (size_t)E * sizeof(unsigned short));
    int* hb = (int*)(ws + off);
    off = align_up(off + (size_t)nblk * N * sizeof(int));
    int* tot = (int*)(ws + off);
    off = align_up(off + (size_t)N * sizeof(int));
    int* base = (int*)(ws + off);
    off = align_up(off + (size_t)N * sizeof(int));
    int* perm = (int*)(ws + off);
    off = align_up(off + (size_t)E * sizeof(int));
    int* snode = (int*)(ws + off);
    off = align_up(off + (size_t)E * sizeof(int));

    hipMemsetAsync(d_out, 0, (size_t)out_size * sizeof(float), stream);

    convert_weights<<<(NSTAGE * HDIM * HDIM + 255) / 256, 256, 0, stream>>>(W1, W2, Wlin, wbf);

    // atomic-free counting sort
    hist_rank_kernel<<<nblk, 1024, 0, stream>>>(tgt, rank, hb, E, N);
    colsum_kernel<<<(N + 255) / 256, 256, 0, stream>>>(hb, tot, nblk, N);
    scan_kernel<<<1, 1024, 0, stream>>>(tot, base, N);
    offsets_kernel<<<(N + 255) / 256, 256, 0, stream>>>(hb, base, nblk, N);
    emit_perm_kernel<<<(E + 255) / 256, 256, 0, stream>>>(tgt, rank, hb, perm, snode, E, N);

    int ntiles  = (E + 31) / 32;
    int nblocks = (ntiles + 3) / 4;
    fused_mlp_scatter<<<nblocks, 256, 0, stream>>>(m, perm, snode, wbf, b1, b2, blin,
                                                   (float*)d_out, E, ntiles);
}

// Round 8
// 545.355 us; speedup vs baseline: 1.3821x; 1.0472x over previous
//
#include <hip/hip_runtime.h>
#include <hip/hip_bf16.h>

#define HDIM 128
#define NSTAGE 7
#define CHUNK_LOG 13
#define CHUNK (1 << CHUNK_LOG)

typedef __bf16 bf16x8 __attribute__((ext_vector_type(8)));
typedef __bf16 bf16x2 __attribute__((ext_vector_type(2)));
typedef float floatx16 __attribute__((ext_vector_type(16)));
typedef float floatx4 __attribute__((ext_vector_type(4)));
typedef int intx4 __attribute__((ext_vector_type(4)));

__device__ __forceinline__ float silu_f(float x) {
    return x * __builtin_amdgcn_rcpf(1.0f + __expf(-x));
}

__device__ __forceinline__ int pack2(float a, float b) {
    bf16x2 h;
    h[0] = (__bf16)a;
    h[1] = (__bf16)b;
    return __builtin_bit_cast(int, h);
}

__device__ __forceinline__ void unpack2f(int p, float& x0, float& x1) {
    bf16x2 h = __builtin_bit_cast(bf16x2, p);
    x0 = (float)h[0];
    x1 = (float)h[1];
}

__device__ __forceinline__ bf16x8 frag_from(int w0, int w1, int w2, int w3) {
    intx4 v; v[0] = w0; v[1] = w1; v[2] = w2; v[3] = w3;
    return __builtin_bit_cast(bf16x8, v);
}

// async global->LDS, 16B per lane; LDS dest = wave-uniform base + lane*16.
__device__ __forceinline__ void gload_lds16(const void* g, void* l) {
    __builtin_amdgcn_global_load_lds(
        (const __attribute__((address_space(1))) unsigned int*)g,
        (__attribute__((address_space(3))) unsigned int*)l, 16, 0, 0);
}

// Weights -> bf16. Stage order W1[0],W2[0],W1[1],W2[1],W1[2],W2[2],Wlin.
// Per stage, two contiguous 16KB HALF-TILES (k<64 | k>=64), each [mrow][64]
// with the XOR swizzle applied within the half:
//   elem [s][mrow][k] -> s*16384 + (k>>6)*8192 + mrow*64
//                        + (( ((k>>3)&7) ^ (mrow&7) ) << 3) + (k&7)
__global__ void convert_weights(const float* __restrict__ W1,
                                const float* __restrict__ W2,
                                const float* __restrict__ Wlin,
                                __bf16* __restrict__ dst) {
    int idx = blockIdx.x * blockDim.x + threadIdx.x;
    if (idx >= NSTAGE * HDIM * HDIM) return;
    int s    = idx >> 14;
    int rem  = idx & 16383;
    int mrow = rem >> 7;
    int k    = rem & 127;
    const float* src;
    if (s == 6) src = Wlin;
    else {
        int l = s >> 1;
        src = ((s & 1) ? W2 : W1) + l * HDIM * HDIM;
    }
    float v = src[mrow * HDIM + k];
    int khalf = k >> 6;
    int c     = (k >> 3) & 7;
    int dsti  = (s << 14) + (khalf << 13) + (mrow << 6)
              + (((c ^ (mrow & 7)) << 3) | (k & 7));
    dst[dsti] = (__bf16)v;
}

// ---- atomic-free counting sort of edges by target node ----
__global__ __launch_bounds__(1024) void hist_rank_kernel(
    const int* __restrict__ tgt,
    unsigned short* __restrict__ rank,
    int* __restrict__ hb,
    int E, int N)
{
    __shared__ int lh[10240];   // N = 10000 for this problem
    for (int i = threadIdx.x; i < N; i += 1024) lh[i] = 0;
    __syncthreads();
    int ebase = blockIdx.x << CHUNK_LOG;
    int eend  = min(ebase + CHUNK, E);
    for (int e = ebase + (int)threadIdx.x; e < eend; e += 1024) {
        int node = tgt[e];
        int r = atomicAdd(&lh[node], 1);   // LDS atomic — fast
        rank[e] = (unsigned short)r;       // coalesced
    }
    __syncthreads();
    int* row = hb + (size_t)blockIdx.x * N;
    for (int i = threadIdx.x; i < N; i += 1024) row[i] = lh[i];  // coalesced
}

__global__ void colsum_kernel(const int* __restrict__ hb, int* __restrict__ tot,
                              int nblk, int N) {
    int n = blockIdx.x * blockDim.x + threadIdx.x;
    if (n >= N) return;
    int s = 0;
    for (int b = 0; b < nblk; ++b) s += hb[(size_t)b * N + n];
    tot[n] = s;
}

__global__ __launch_bounds__(1024) void scan_kernel(const int* __restrict__ hist,
                                                    int* __restrict__ cursor, int N) {
    __shared__ int part[1024];
    int t = threadIdx.x;
    int per = (N + 1023) >> 10;
    int lo = t * per, hi = min(lo + per, N);
    int s = 0;
    for (int i = lo; i < hi; ++i) s += hist[i];
    part[t] = s;
    __syncthreads();
    for (int d = 1; d < 1024; d <<= 1) {
        int v = (t >= d) ? part[t - d] : 0;
        __syncthreads();
        part[t] += v;
        __syncthreads();
    }
    int off = (t == 0) ? 0 : part[t - 1];
    for (int i = lo; i < hi; ++i) { cursor[i] = off; off += hist[i]; }
}

__global__ void offsets_kernel(int* __restrict__ hb, const int* __restrict__ base,
                               int nblk, int N) {
    int n = blockIdx.x * blockDim.x + threadIdx.x;
    if (n >= N) return;
    int run = base[n];
    for (int b = 0; b < nblk; ++b) {
        size_t idx = (size_t)b * N + n;
        int c = hb[idx];
        hb[idx] = run;
        run += c;
    }
}

__global__ void emit_perm_kernel(const int* __restrict__ tgt,
                                 const unsigned short* __restrict__ rank,
                                 const int* __restrict__ hb,
                                 int* __restrict__ perm, int* __restrict__ snode,
                                 int E, int N) {
    int e = blockIdx.x * blockDim.x + threadIdx.x;
    if (e >= E) return;
    int node = tgt[e];
    int b = e >> CHUNK_LOG;
    int pos = hb[(size_t)b * N + node] + (int)rank[e];
    perm[pos] = e;
    snode[pos] = node;
}

// One wave owns 32 sorted-order edges end-to-end.
// Matmuls transposed: D[feat][edge] via mfma_f32_32x32x16_bf16.
// C/D: edge=lane&31, feat=mb*32+(reg&3)+8*(reg>>2)+4*(lane>>5).
//
// Activations entirely in registers (shfl_xor cross-half exchange, r3/r4).
// Residual X packed bf16 (r7, spill-free at (256,3)).
//
// r8: T3/T4 pipeline for weight staging. RING OF THREE 16KB half-tile
// buffers; half h+2 issued while computing half h (~2 half-periods of
// latency cover). Sync per half = `s_waitcnt vmcnt(4)` (own current-half
// loads complete, newest 4 in flight) + RAW s_barrier — NO vmcnt(0) drain
// in the loop (r6/r7 exposed full L2 latency twice per stage via
// __syncthreads drains; that canceled the occupancy win).
// To keep vmcnt FIFO-counting exact, the loop contains no other VMEM:
// biases are staged to LDS in the prologue. LDS = 48KB ring + 3.5KB bias
// = 51.5KB <= 53.3KB -> still 3 blocks/CU.
__global__ __launch_bounds__(256, 3) void fused_mlp_scatter(
    const float* __restrict__ m,
    const int* __restrict__ perm,
    const int* __restrict__ snode,
    const __bf16* __restrict__ wmats,
    const float* __restrict__ b1,
    const float* __restrict__ b2,
    const float* __restrict__ blin,
    float* __restrict__ out,
    int E, int ntiles)
{
    __shared__ __align__(16) char smem[52736];   // 3x16KB ring | epi overlay; +896 f32 bias
    float* ybuf     = (float*)smem;              // 4*32*68 f32 epilogue overlay
    float* bias_lds = (float*)(smem + 49152);    // 7 * 128 f32

    const int tid  = threadIdx.x;
    const int w    = tid >> 6;
    const int lane = tid & 63;
    const int l31  = lane & 31;
    const int half = lane >> 5;

    const int tile    = blockIdx.x * 4 + w;
    const bool activeW = (tile < ntiles);
    const int pos = tile * 32 + l31;
    const bool evalid = activeW && (pos < E);

    int eidx = 0, mynode = 0;

    int Xp[4][4][2];   // residual X, packed bf16 (2 feats per int)
    floatx16 acc[4];
    int bw[8][4];      // B-fragments for current stage, fully static-indexed

    #define BUILD_BW(KS, VA0,VA1,VA2,VA3, VB0,VB1,VB2,VB3) do {              \
        int A0_ = pack2((VA0), (VA1)); int A1_ = pack2((VA2), (VA3));        \
        int B0_ = pack2((VB0), (VB1)); int B1_ = pack2((VB2), (VB3));        \
        int N0_ = half ? A0_ : B0_;  int N1_ = half ? A1_ : B1_;             \
        int S0_ = __shfl_xor(N0_, 32, 64);                                   \
        int S1_ = __shfl_xor(N1_, 32, 64);                                   \
        bw[KS][0] = half ? S0_ : A0_;  bw[KS][1] = half ? S1_ : A1_;         \
        bw[KS][2] = half ? B0_ : S0_;  bw[KS][3] = half ? B1_ : S1_;         \
    } while (0)

    // stage one 16KB half-tile (hs = 0..13) into ring buf (0..2).
    // 256 threads x 16B = 4KB/issue; 4 issues. Dest = uniform base + lane*16.
    #define STAGE_HALF(HS, BUF) do {                                         \
        const char* g_ = (const char*)wmats + ((HS) << 14) + tid * 16;       \
        char* l_ = smem + ((BUF) << 14) + tid * 16;                          \
        _Pragma("unroll")                                                    \
        for (int i_ = 0; i_ < 4; ++i_)                                       \
            gload_lds16(g_ + i_ * 4096, l_ + i_ * 4096);                     \
    } while (0)

    // prologue: issue halves 0 and 1 into ring bufs 0 and 1
    STAGE_HALF(0, 0);
    STAGE_HALF(1, 1);

    if (evalid) { eidx = perm[pos]; mynode = snode[pos]; }

    // stage biases to LDS (keeps loop free of non-staging VMEM)
    for (int i = tid; i < NSTAGE * HDIM; i += 256) {
        int s = i >> 7, f = i & 127;
        float v = (s == 6) ? blin[f]
                : ((s & 1) ? b2[(s >> 1) * HDIM + f] : b1[(s >> 1) * HDIM + f]);
        bias_lds[i] = v;
    }

    if (activeW) {
        const float* mrow = m + (size_t)eidx * HDIM;
        #pragma unroll
        for (int mb = 0; mb < 4; ++mb) {
            floatx4 xv[4];
            #pragma unroll
            for (int q = 0; q < 4; ++q)
                xv[q] = *(const floatx4*)(mrow + mb * 32 + q * 8 + half * 4);
            #pragma unroll
            for (int q = 0; q < 4; ++q) {
                Xp[mb][q][0] = pack2(xv[q][0], xv[q][1]);
                Xp[mb][q][1] = pack2(xv[q][2], xv[q][3]);
            }
            BUILD_BW(2 * mb,
                silu_f(xv[0][0]), silu_f(xv[0][1]), silu_f(xv[0][2]), silu_f(xv[0][3]),
                silu_f(xv[1][0]), silu_f(xv[1][1]), silu_f(xv[1][2]), silu_f(xv[1][3]));
            BUILD_BW(2 * mb + 1,
                silu_f(xv[2][0]), silu_f(xv[2][1]), silu_f(xv[2][2]), silu_f(xv[2][3]),
                silu_f(xv[3][0]), silu_f(xv[3][1]), silu_f(xv[3][2]), silu_f(xv[3][3]));
        }
    }

    // full sync once: drains prologue VMEM (incl. halves 0,1) + bias ds_writes.
    // From here on, vmcnt stream = gload_lds only, 4 per half, FIFO-counted.
    __syncthreads();

    #pragma unroll
    for (int s = 0; s < NSTAGE; ++s) {
        // ======== half A: h = 2s, ring buf (2s)%3 ========
        if (s > 0) {
            // own half-A loads (issued 2 halves ago) done; allow newest 4 in flight
            asm volatile("s_waitcnt vmcnt(4)" ::: "memory");
            __builtin_amdgcn_sched_barrier(0);
            __builtin_amdgcn_s_barrier();      // all waves' half-A loads visible
            __builtin_amdgcn_sched_barrier(0);
        }
        // issue half h+2 into buf (h+2)%3 (its readers finished before the barrier)
        if (2 * s + 2 <= 13) STAGE_HALF(2 * s + 2, (2 * s + 2) % 3);

        if (activeW) {
            // acc C-init = bias for this stage (from LDS)
            const float* bl = bias_lds + s * HDIM;
            #pragma unroll
            for (int mb = 0; mb < 4; ++mb)
                #pragma unroll
                for (int q = 0; q < 4; ++q) {
                    floatx4 bv = *(const floatx4*)(bl + mb * 32 + q * 8 + half * 4);
                    #pragma unroll
                    for (int j = 0; j < 4; ++j) acc[mb][q * 4 + j] = bv[j];
                }
            const __bf16* wl = (const __bf16*)(smem + ((2 * s) % 3) * 16384);
            #pragma unroll
            for (int lks = 0; lks < 4; ++lks) {
                bf16x8 bfrag = frag_from(bw[lks][0], bw[lks][1], bw[lks][2], bw[lks][3]);
                int krl = lks * 2 + half;
                #pragma unroll
                for (int mb = 0; mb < 4; ++mb) {
                    int mr = mb * 32 + l31;
                    bf16x8 afrag = *(const bf16x8*)(&wl[(mr << 6) + ((krl ^ (mr & 7)) << 3)]);
                    acc[mb] = __builtin_amdgcn_mfma_f32_32x32x16_bf16(afrag, bfrag, acc[mb], 0, 0, 0);
                }
            }
        }

        // ======== half B: h = 2s+1, ring buf (2s+1)%3 ========
        if (s == 6) asm volatile("s_waitcnt vmcnt(0)" ::: "memory");  // last half: nothing newer
        else        asm volatile("s_waitcnt vmcnt(4)" ::: "memory");
        __builtin_amdgcn_sched_barrier(0);
        __builtin_amdgcn_s_barrier();
        __builtin_amdgcn_sched_barrier(0);
        if (2 * s + 3 <= 13) STAGE_HALF(2 * s + 3, (2 * s + 3) % 3);

        if (activeW) {
            const __bf16* wl = (const __bf16*)(smem + ((2 * s + 1) % 3) * 16384);
            #pragma unroll
            for (int lks = 0; lks < 4; ++lks) {
                bf16x8 bfrag = frag_from(bw[4 + lks][0], bw[4 + lks][1],
                                         bw[4 + lks][2], bw[4 + lks][3]);
                int krl = lks * 2 + half;
                #pragma unroll
                for (int mb = 0; mb < 4; ++mb) {
                    int mr = mb * 32 + l31;
                    bf16x8 afrag = *(const bf16x8*)(&wl[(mr << 6) + ((krl ^ (mr & 7)) << 3)]);
                    acc[mb] = __builtin_amdgcn_mfma_f32_32x32x16_bf16(afrag, bfrag, acc[mb], 0, 0, 0);
                }
            }

            if (s == 6) {
                // final silu IN-PLACE into acc (bias already included via C-init)
                #pragma unroll
                for (int mb = 0; mb < 4; ++mb)
                    #pragma unroll
                    for (int r = 0; r < 16; ++r)
                        acc[mb][r] = silu_f(acc[mb][r]);
            } else if ((s & 1) == 0) {
                // h = silu(acc); X unchanged; build next-stage B-fragments
                #pragma unroll
                for (int ks = 0; ks < 8; ++ks) {
                    int mb = ks >> 1, qa = (ks & 1) * 2, qb = qa + 1;
                    BUILD_BW(ks,
                        silu_f(acc[mb][qa * 4 + 0]), silu_f(acc[mb][qa * 4 + 1]),
                        silu_f(acc[mb][qa * 4 + 2]), silu_f(acc[mb][qa * 4 + 3]),
                        silu_f(acc[mb][qb * 4 + 0]), silu_f(acc[mb][qb * 4 + 1]),
                        silu_f(acc[mb][qb * 4 + 2]), silu_f(acc[mb][qb * 4 + 3]));
                }
            } else {
                // X += acc (residual, bf16-packed); act = (s==5) ? X : silu(X)
                #pragma unroll
                for (int ks = 0; ks < 8; ++ks) {
                    int mb = ks >> 1, qa = (ks & 1) * 2, qb = qa + 1;
                    float va[4], vb[4];
                    {
                        float x0, x1, x2, x3;
                        unpack2f(Xp[mb][qa][0], x0, x1);
                        unpack2f(Xp[mb][qa][1], x2, x3);
                        x0 += acc[mb][qa * 4 + 0]; x1 += acc[mb][qa * 4 + 1];
                        x2 += acc[mb][qa * 4 + 2]; x3 += acc[mb][qa * 4 + 3];
                        Xp[mb][qa][0] = pack2(x0, x1);
                        Xp[mb][qa][1] = pack2(x2, x3);
                        va[0] = (s == 5) ? x0 : silu_f(x0);
                        va[1] = (s == 5) ? x1 : silu_f(x1);
                        va[2] = (s == 5) ? x2 : silu_f(x2);
                        va[3] = (s == 5) ? x3 : silu_f(x3);
                    }
                    {
                        float x0, x1, x2, x3;
                        unpack2f(Xp[mb][qb][0], x0, x1);
                        unpack2f(Xp[mb][qb][1], x2, x3);
                        x0 += acc[mb][qb * 4 + 0]; x1 += acc[mb][qb * 4 + 1];
                        x2 += acc[mb][qb * 4 + 2]; x3 += acc[mb][qb * 4 + 3];
                        Xp[mb][qb][0] = pack2(x0, x1);
                        Xp[mb][qb][1] = pack2(x2, x3);
                        vb[0] = (s == 5) ? x0 : silu_f(x0);
                        vb[1] = (s == 5) ? x1 : silu_f(x1);
                        vb[2] = (s == 5) ? x2 : silu_f(x2);
                        vb[3] = (s == 5) ? x3 : silu_f(x3);
                    }
                    BUILD_BW(ks, va[0], va[1], va[2], va[3],
                                 vb[0], vb[1], vb[2], vb[3]);
                }
            }
        }
    }

    // ---- epilogue: all waves done with weight LDS before ybuf overlay ----
    // Two 64-feat passes through a 4*32*68-float buffer (wave-private rows).
    __syncthreads();
    if (activeW) {
        const int ebase = tile * 32;
        const int cnt = min(32, E - ebase);
        float* yrow = ybuf + (w * 32 + l31) * 68;
        const float* yb = ybuf + w * 32 * 68;
        #pragma unroll
        for (int p = 0; p < 2; ++p) {
            #pragma unroll
            for (int mbh = 0; mbh < 2; ++mbh) {
                int mb = 2 * p + mbh;
                #pragma unroll
                for (int q = 0; q < 4; ++q) {
                    int f0 = mbh * 32 + q * 8 + half * 4;   // within-pass feat
                    floatx4 v;
                    for (int j = 0; j < 4; ++j) v[j] = acc[mb][q * 4 + j];
                    *(floatx4*)(yrow + f0) = v;
                }
            }
            // wave-private segmented accumulate + atomic row-writes
            int cur = __builtin_amdgcn_readlane(mynode, 0);
            float a0 = 0.f;
            for (int e = 0; e < cnt; ++e) {
                int node = __builtin_amdgcn_readlane(mynode, e);
                if (node != cur) {
                    unsafeAtomicAdd(out + (size_t)cur * HDIM + p * 64 + lane, a0);
                    cur = node; a0 = 0.f;
                }
                a0 += yb[e * 68 + lane];
            }
            unsafeAtomicAdd(out + (size_t)cur * HDIM + p * 64 + lane, a0);
        }
    }
    #undef BUILD_BW
    #undef STAGE_HALF
}

extern "C" void kernel_launch(void* const* d_in, const int* in_sizes, int n_in,
                              void* d_out, int out_size, void* d_ws, size_t ws_size,
                              hipStream_t stream) {
    const float* m      = (const float*)d_in[0];
    const int* edge_idx = (const int*)d_in[1];
    const float* W1     = (const float*)d_in[3];
    const float* b1     = (const float*)d_in[4];
    const float* W2     = (const float*)d_in[5];
    const float* b2     = (const float*)d_in[6];
    const float* Wlin   = (const float*)d_in[7];
    const float* blin   = (const float*)d_in[8];

    int E = in_sizes[0] / HDIM;
    int N = out_size / HDIM;
    const int* tgt = edge_idx + E;

    int nblk = (E + CHUNK - 1) >> CHUNK_LOG;   // 8192-edge chunks (62 for E=500k)

    // workspace layout (256B-aligned)
    char* ws = (char*)d_ws;
    size_t off = 0;
    auto align_up = [](size_t v) { return (v + 255) & ~(size_t)255; };

    __bf16* wbf = (__bf16*)(ws + off);
    off = align_up(off + (size_t)NSTAGE * HDIM * HDIM * sizeof(__bf16));
    unsigned short* rank = (unsigned short*)(ws + off);
    off = align_up(off + (size_t)E * sizeof(unsigned short));
    int* hb = (int*)(ws + off);
    off = align_up(off + (size_t)nblk * N * sizeof(int));
    int* tot = (int*)(ws + off);
    off = align_up(off + (size_t)N * sizeof(int));
    int* base = (int*)(ws + off);
    off = align_up(off + (size_t)N * sizeof(int));
    int* perm = (int*)(ws + off);
    off = align_up(off + (size_t)E * sizeof(int));
    int* snode = (int*)(ws + off);
    off = align_up(off + (size_t)E * sizeof(int));

    hipMemsetAsync(d_out, 0, (size_t)out_size * sizeof(float), stream);

    convert_weights<<<(NSTAGE * HDIM * HDIM + 255) / 256, 256, 0, stream>>>(W1, W2, Wlin, wbf);

    // atomic-free counting sort
    hist_rank_kernel<<<nblk, 1024, 0, stream>>>(tgt, rank, hb, E, N);
    colsum_kernel<<<(N + 255) / 256, 256, 0, stream>>>(hb, tot, nblk, N);
    scan_kernel<<<1, 1024, 0, stream>>>(tot, base, N);
    offsets_kernel<<<(N + 255) / 256, 256, 0, stream>>>(hb, base, nblk, N);
    emit_perm_kernel<<<(E + 255) / 256, 256, 0, stream>>>(tgt, rank, hb, perm, snode, E, N);

    int ntiles  = (E + 31) / 32;
    int nblocks = (ntiles + 3) / 4;
    fused_mlp_scatter<<<nblocks, 256, 0, stream>>>(m, perm, snode, wbf, b1, b2, blin,
                                                   (float*)d_out, E, ntiles);
}

// Round 10
// 530.768 us; speedup vs baseline: 1.4201x; 1.0275x over previous
//
#include <hip/hip_runtime.h>
#include <hip/hip_bf16.h>

#define HDIM 128
#define NSTAGE 7
#define CHUNK_LOG 13
#define CHUNK (1 << CHUNK_LOG)

typedef __bf16 bf16x8 __attribute__((ext_vector_type(8)));
typedef __bf16 bf16x2 __attribute__((ext_vector_type(2)));
typedef float floatx16 __attribute__((ext_vector_type(16)));
typedef float floatx4 __attribute__((ext_vector_type(4)));
typedef int intx4 __attribute__((ext_vector_type(4)));

__device__ __forceinline__ float silu_f(float x) {
    return x * __builtin_amdgcn_rcpf(1.0f + __expf(-x));
}

__device__ __forceinline__ int pack2(float a, float b) {
    bf16x2 h;
    h[0] = (__bf16)a;
    h[1] = (__bf16)b;
    return __builtin_bit_cast(int, h);
}

__device__ __forceinline__ void unpack2f(int p, float& x0, float& x1) {
    bf16x2 h = __builtin_bit_cast(bf16x2, p);
    x0 = (float)h[0];
    x1 = (float)h[1];
}

__device__ __forceinline__ bf16x8 frag_from(int w0, int w1, int w2, int w3) {
    intx4 v; v[0] = w0; v[1] = w1; v[2] = w2; v[3] = w3;
    return __builtin_bit_cast(bf16x8, v);
}

// async global->LDS, 16B per lane; LDS dest = wave-uniform base + lane*16.
__device__ __forceinline__ void gload_lds16(const void* g, void* l) {
    __builtin_amdgcn_global_load_lds(
        (const __attribute__((address_space(1))) unsigned int*)g,
        (__attribute__((address_space(3))) unsigned int*)l, 16, 0, 0);
}

// Weights -> bf16. Stage order W1[0],W2[0],W1[1],W2[1],W1[2],W2[2],Wlin.
// r10: CONTRACTION-AXIS PERMUTATION pi = swap(bit2, bit3) of k. We store
// W[m][slot] = W_orig[m][pi(slot)] (pi is an involution: dst slot for source
// k is pi(k)). With this, the MFMA B-slot (ks, half, j) needs feat
// pi(ks*16+half*8+j) = ks*16 + half*4 + (j&3) + (j>=4 ? 8 : 0) — exactly the
// lane's OWN acc quads (qa, qb) in order -> the cross-half register exchange
// is eliminated entirely. pi permutes within each 16-wide k-group, so each
// MFMA sums the same 16 feats as before (bitwise-identical results).
// Layout within a stage: two 16KB half-tiles (slot<64 | slot>=64), each
// [mrow][64] with XOR swizzle on 16B granules (as r6).
__global__ void convert_weights(const float* __restrict__ W1,
                                const float* __restrict__ W2,
                                const float* __restrict__ Wlin,
                                __bf16* __restrict__ dst) {
    int idx = blockIdx.x * blockDim.x + threadIdx.x;
    if (idx >= NSTAGE * HDIM * HDIM) return;
    int s    = idx >> 14;
    int rem  = idx & 16383;
    int mrow = rem >> 7;
    int k    = rem & 127;
    const float* src;
    if (s == 6) src = Wlin;
    else {
        int l = s >> 1;
        src = ((s & 1) ? W2 : W1) + l * HDIM * HDIM;
    }
    float v = src[mrow * HDIM + k];
    int kd    = (k & ~12) | ((k & 4) << 1) | ((k & 8) >> 1);  // swap bits 2,3
    int khalf = kd >> 6;
    int c     = (kd >> 3) & 7;
    int dsti  = (s << 14) + (khalf << 13) + (mrow << 6)
              + (((c ^ (mrow & 7)) << 3) | (kd & 7));
    dst[dsti] = (__bf16)v;
}

// ---- atomic-free counting sort of edges by target node ----
__global__ __launch_bounds__(1024) void hist_rank_kernel(
    const int* __restrict__ tgt,
    unsigned short* __restrict__ rank,
    int* __restrict__ hb,
    int E, int N)
{
    __shared__ int lh[10240];   // N = 10000 for this problem
    for (int i = threadIdx.x; i < N; i += 1024) lh[i] = 0;
    __syncthreads();
    int ebase = blockIdx.x << CHUNK_LOG;
    int eend  = min(ebase + CHUNK, E);
    for (int e = ebase + (int)threadIdx.x; e < eend; e += 1024) {
        int node = tgt[e];
        int r = atomicAdd(&lh[node], 1);   // LDS atomic — fast
        rank[e] = (unsigned short)r;       // coalesced
    }
    __syncthreads();
    int* row = hb + (size_t)blockIdx.x * N;
    for (int i = threadIdx.x; i < N; i += 1024) row[i] = lh[i];  // coalesced
}

__global__ void colsum_kernel(const int* __restrict__ hb, int* __restrict__ tot,
                              int nblk, int N) {
    int n = blockIdx.x * blockDim.x + threadIdx.x;
    if (n >= N) return;
    int s = 0;
    for (int b = 0; b < nblk; ++b) s += hb[(size_t)b * N + n];
    tot[n] = s;
}

__global__ __launch_bounds__(1024) void scan_kernel(const int* __restrict__ hist,
                                                    int* __restrict__ cursor, int N) {
    __shared__ int part[1024];
    int t = threadIdx.x;
    int per = (N + 1023) >> 10;
    int lo = t * per, hi = min(lo + per, N);
    int s = 0;
    for (int i = lo; i < hi; ++i) s += hist[i];
    part[t] = s;
    __syncthreads();
    for (int d = 1; d < 1024; d <<= 1) {
        int v = (t >= d) ? part[t - d] : 0;
        __syncthreads();
        part[t] += v;
        __syncthreads();
    }
    int off = (t == 0) ? 0 : part[t - 1];
    for (int i = lo; i < hi; ++i) { cursor[i] = off; off += hist[i]; }
}

__global__ void offsets_kernel(int* __restrict__ hb, const int* __restrict__ base,
                               int nblk, int N) {
    int n = blockIdx.x * blockDim.x + threadIdx.x;
    if (n >= N) return;
    int run = base[n];
    for (int b = 0; b < nblk; ++b) {
        size_t idx = (size_t)b * N + n;
        int c = hb[idx];
        hb[idx] = run;
        run += c;
    }
}

__global__ void emit_perm_kernel(const int* __restrict__ tgt,
                                 const unsigned short* __restrict__ rank,
                                 const int* __restrict__ hb,
                                 int* __restrict__ perm, int* __restrict__ snode,
                                 int E, int N) {
    int e = blockIdx.x * blockDim.x + threadIdx.x;
    if (e >= E) return;
    int node = tgt[e];
    int b = e >> CHUNK_LOG;
    int pos = hb[(size_t)b * N + node] + (int)rank[e];
    perm[pos] = e;
    snode[pos] = node;
}

// One wave owns 32 sorted-order edges end-to-end.
// Matmuls transposed: D[feat][edge] via mfma_f32_32x32x16_bf16.
// C/D: edge=lane&31, feat=mb*32+(reg&3)+8*(reg>>2)+4*(lane>>5).
//
// Activations entirely in registers, ZERO cross-lane exchange (r10): the
// weight contraction axis is stored pre-permuted (pi = swap bit2/bit3, see
// convert_weights), so each lane's B-fragment for slot-group ks is its own
// acc quads (qa, qb) packed to bf16 — BUILD_BW is just 4 v_cvt packs.
//
// Residual X packed bf16 (r7). T3/T4 ring-of-3 16KB half-tile staging with
// counted `s_waitcnt vmcnt(4)` + raw s_barrier (r8) — no vmcnt(0) drain in
// the loop; biases staged to LDS so the vmcnt FIFO stays exact.
__global__ __launch_bounds__(256, 3) void fused_mlp_scatter(
    const float* __restrict__ m,
    const int* __restrict__ perm,
    const int* __restrict__ snode,
    const __bf16* __restrict__ wmats,
    const float* __restrict__ b1,
    const float* __restrict__ b2,
    const float* __restrict__ blin,
    float* __restrict__ out,
    int E, int ntiles)
{
    __shared__ __align__(16) char smem[52736];   // 3x16KB ring | epi overlay; +896 f32 bias
    float* ybuf     = (float*)smem;              // 4*32*68 f32 epilogue overlay
    float* bias_lds = (float*)(smem + 49152);    // 7 * 128 f32

    const int tid  = threadIdx.x;
    const int w    = tid >> 6;
    const int lane = tid & 63;
    const int l31  = lane & 31;
    const int half = lane >> 5;

    const int tile    = blockIdx.x * 4 + w;
    const bool activeW = (tile < ntiles);
    const int pos = tile * 32 + l31;
    const bool evalid = activeW && (pos < E);

    int eidx = 0, mynode = 0;

    int Xp[4][4][2];   // residual X, packed bf16 (2 feats per int)
    floatx16 acc[4];
    int bw[8][4];      // B-fragments for current stage, fully static-indexed

    // zero-shuffle: own qa quad -> words 0,1; own qb quad -> words 2,3.
    #define BUILD_BW(KS, VA0,VA1,VA2,VA3, VB0,VB1,VB2,VB3) do {              \
        bw[KS][0] = pack2((VA0), (VA1)); bw[KS][1] = pack2((VA2), (VA3));    \
        bw[KS][2] = pack2((VB0), (VB1)); bw[KS][3] = pack2((VB2), (VB3));    \
    } while (0)

    // stage one 16KB half-tile (hs = 0..13) into ring buf (0..2).
    // 256 threads x 16B = 4KB/issue; 4 issues. Dest = uniform base + lane*16.
    #define STAGE_HALF(HS, BUF) do {                                         \
        const char* g_ = (const char*)wmats + ((HS) << 14) + tid * 16;       \
        char* l_ = smem + ((BUF) << 14) + tid * 16;                          \
        _Pragma("unroll")                                                    \
        for (int i_ = 0; i_ < 4; ++i_)                                       \
            gload_lds16(g_ + i_ * 4096, l_ + i_ * 4096);                     \
    } while (0)

    // prologue: issue halves 0 and 1 into ring bufs 0 and 1
    STAGE_HALF(0, 0);
    STAGE_HALF(1, 1);

    if (evalid) { eidx = perm[pos]; mynode = snode[pos]; }

    // stage biases to LDS (keeps loop free of non-staging VMEM)
    for (int i = tid; i < NSTAGE * HDIM; i += 256) {
        int s = i >> 7, f = i & 127;
        float v = (s == 6) ? blin[f]
                : ((s & 1) ? b2[(s >> 1) * HDIM + f] : b1[(s >> 1) * HDIM + f]);
        bias_lds[i] = v;
    }

    if (activeW) {
        const float* mrow = m + (size_t)eidx * HDIM;
        #pragma unroll
        for (int mb = 0; mb < 4; ++mb) {
            floatx4 xv[4];
            #pragma unroll
            for (int q = 0; q < 4; ++q)
                xv[q] = *(const floatx4*)(mrow + mb * 32 + q * 8 + half * 4);
            #pragma unroll
            for (int q = 0; q < 4; ++q) {
                Xp[mb][q][0] = pack2(xv[q][0], xv[q][1]);
                Xp[mb][q][1] = pack2(xv[q][2], xv[q][3]);
            }
            BUILD_BW(2 * mb,
                silu_f(xv[0][0]), silu_f(xv[0][1]), silu_f(xv[0][2]), silu_f(xv[0][3]),
                silu_f(xv[1][0]), silu_f(xv[1][1]), silu_f(xv[1][2]), silu_f(xv[1][3]));
            BUILD_BW(2 * mb + 1,
                silu_f(xv[2][0]), silu_f(xv[2][1]), silu_f(xv[2][2]), silu_f(xv[2][3]),
                silu_f(xv[3][0]), silu_f(xv[3][1]), silu_f(xv[3][2]), silu_f(xv[3][3]));
        }
    }

    // full sync once: drains prologue VMEM (incl. halves 0,1) + bias ds_writes.
    // From here on, vmcnt stream = gload_lds only, 4 per half, FIFO-counted.
    __syncthreads();

    #pragma unroll
    for (int s = 0; s < NSTAGE; ++s) {
        // ======== half A: slots 0..63, ring buf (2s)%3 ========
        if (s > 0) {
            // own half-A loads (issued 2 halves ago) done; allow newest 4 in flight
            asm volatile("s_waitcnt vmcnt(4)" ::: "memory");
            __builtin_amdgcn_sched_barrier(0);
            __builtin_amdgcn_s_barrier();      // all waves' half-A loads visible
            __builtin_amdgcn_sched_barrier(0);
        }
        // issue half h+2 into buf (h+2)%3 (its readers finished before the barrier)
        if (2 * s + 2 <= 13) STAGE_HALF(2 * s + 2, (2 * s + 2) % 3);

        if (activeW) {
            // acc C-init = bias for this stage (from LDS)
            const float* bl = bias_lds + s * HDIM;
            #pragma unroll
            for (int mb = 0; mb < 4; ++mb)
                #pragma unroll
                for (int q = 0; q < 4; ++q) {
                    floatx4 bv = *(const floatx4*)(bl + mb * 32 + q * 8 + half * 4);
                    #pragma unroll
                    for (int j = 0; j < 4; ++j) acc[mb][q * 4 + j] = bv[j];
                }
            const __bf16* wl = (const __bf16*)(smem + ((2 * s) % 3) * 16384);
            #pragma unroll
            for (int lks = 0; lks < 4; ++lks) {
                bf16x8 bfrag = frag_from(bw[lks][0], bw[lks][1], bw[lks][2], bw[lks][3]);
                int krl = lks * 2 + half;
                #pragma unroll
                for (int mb = 0; mb < 4; ++mb) {
                    int mr = mb * 32 + l31;
                    bf16x8 afrag = *(const bf16x8*)(&wl[(mr << 6) + ((krl ^ (mr & 7)) << 3)]);
                    acc[mb] = __builtin_amdgcn_mfma_f32_32x32x16_bf16(afrag, bfrag, acc[mb], 0, 0, 0);
                }
            }
        }

        // ======== half B: slots 64..127, ring buf (2s+1)%3 ========
        if (s == 6) asm volatile("s_waitcnt vmcnt(0)" ::: "memory");  // last half: nothing newer
        else        asm volatile("s_waitcnt vmcnt(4)" ::: "memory");
        __builtin_amdgcn_sched_barrier(0);
        __builtin_amdgcn_s_barrier();
        __builtin_amdgcn_sched_barrier(0);
        if (2 * s + 3 <= 13) STAGE_HALF(2 * s + 3, (2 * s + 3) % 3);

        if (activeW) {
            const __bf16* wl = (const __bf16*)(smem + ((2 * s + 1) % 3) * 16384);
            #pragma unroll
            for (int lks = 0; lks < 4; ++lks) {
                bf16x8 bfrag = frag_from(bw[4 + lks][0], bw[4 + lks][1],
                                         bw[4 + lks][2], bw[4 + lks][3]);
                int krl = lks * 2 + half;
                #pragma unroll
                for (int mb = 0; mb < 4; ++mb) {
                    int mr = mb * 32 + l31;
                    bf16x8 afrag = *(const bf16x8*)(&wl[(mr << 6) + ((krl ^ (mr & 7)) << 3)]);
                    acc[mb] = __builtin_amdgcn_mfma_f32_32x32x16_bf16(afrag, bfrag, acc[mb], 0, 0, 0);
                }
            }

            if (s == 6) {
                // final silu IN-PLACE into acc (bias already included via C-init)
                #pragma unroll
                for (int mb = 0; mb < 4; ++mb)
                    #pragma unroll
                    for (int r = 0; r < 16; ++r)
                        acc[mb][r] = silu_f(acc[mb][r]);
            } else if ((s & 1) == 0) {
                // h = silu(acc); X unchanged; build next-stage B-fragments
                #pragma unroll
                for (int ks = 0; ks < 8; ++ks) {
                    int mb = ks >> 1, qa = (ks & 1) * 2, qb = qa + 1;
                    BUILD_BW(ks,
                        silu_f(acc[mb][qa * 4 + 0]), silu_f(acc[mb][qa * 4 + 1]),
                        silu_f(acc[mb][qa * 4 + 2]), silu_f(acc[mb][qa * 4 + 3]),
                        silu_f(acc[mb][qb * 4 + 0]), silu_f(acc[mb][qb * 4 + 1]),
                        silu_f(acc[mb][qb * 4 + 2]), silu_f(acc[mb][qb * 4 + 3]));
                }
            } else {
                // X += acc (residual, bf16-packed); act = (s==5) ? X : silu(X)
                #pragma unroll
                for (int ks = 0; ks < 8; ++ks) {
                    int mb = ks >> 1, qa = (ks & 1) * 2, qb = qa + 1;
                    float va[4], vb[4];
                    {
                        float x0, x1, x2, x3;
                        unpack2f(Xp[mb][qa][0], x0, x1);
                        unpack2f(Xp[mb][qa][1], x2, x3);
                        x0 += acc[mb][qa * 4 + 0]; x1 += acc[mb][qa * 4 + 1];
                        x2 += acc[mb][qa * 4 + 2]; x3 += acc[mb][qa * 4 + 3];
                        Xp[mb][qa][0] = pack2(x0, x1);
                        Xp[mb][qa][1] = pack2(x2, x3);
                        va[0] = (s == 5) ? x0 : silu_f(x0);
                        va[1] = (s == 5) ? x1 : silu_f(x1);
                        va[2] = (s == 5) ? x2 : silu_f(x2);
                        va[3] = (s == 5) ? x3 : silu_f(x3);
                    }
                    {
                        float x0, x1, x2, x3;
                        unpack2f(Xp[mb][qb][0], x0, x1);
                        unpack2f(Xp[mb][qb][1], x2, x3);
                        x0 += acc[mb][qb * 4 + 0]; x1 += acc[mb][qb * 4 + 1];
                        x2 += acc[mb][qb * 4 + 2]; x3 += acc[mb][qb * 4 + 3];
                        Xp[mb][qb][0] = pack2(x0, x1);
                        Xp[mb][qb][1] = pack2(x2, x3);
                        vb[0] = (s == 5) ? x0 : silu_f(x0);
                        vb[1] = (s == 5) ? x1 : silu_f(x1);
                        vb[2] = (s == 5) ? x2 : silu_f(x2);
                        vb[3] = (s == 5) ? x3 : silu_f(x3);
                    }
                    BUILD_BW(ks, va[0], va[1], va[2], va[3],
                                 vb[0], vb[1], vb[2], vb[3]);
                }
            }
        }
    }

    // ---- epilogue: all waves done with weight LDS before ybuf overlay ----
    // Two 64-feat passes through a 4*32*68-float buffer (wave-private rows).
    __syncthreads();
    if (activeW) {
        const int ebase = tile * 32;
        const int cnt = min(32, E - ebase);
        float* yrow = ybuf + (w * 32 + l31) * 68;
        const float* yb = ybuf + w * 32 * 68;
        #pragma unroll
        for (int p = 0; p < 2; ++p) {
            #pragma unroll
            for (int mbh = 0; mbh < 2; ++mbh) {
                int mb = 2 * p + mbh;
                #pragma unroll
                for (int q = 0; q < 4; ++q) {
                    int f0 = mbh * 32 + q * 8 + half * 4;   // within-pass feat
                    floatx4 v;
                    for (int j = 0; j < 4; ++j) v[j] = acc[mb][q * 4 + j];
                    *(floatx4*)(yrow + f0) = v;
                }
            }
            // wave-private segmented accumulate + atomic row-writes
            int cur = __builtin_amdgcn_readlane(mynode, 0);
            float a0 = 0.f;
            for (int e = 0; e < cnt; ++e) {
                int node = __builtin_amdgcn_readlane(mynode, e);
                if (node != cur) {
                    unsafeAtomicAdd(out + (size_t)cur * HDIM + p * 64 + lane, a0);
                    cur = node; a0 = 0.f;
                }
                a0 += yb[e * 68 + lane];
            }
            unsafeAtomicAdd(out + (size_t)cur * HDIM + p * 64 + lane, a0);
        }
    }
    #undef BUILD_BW
    #undef STAGE_HALF
}

extern "C" void kernel_launch(void* const* d_in, const int* in_sizes, int n_in,
                              void* d_out, int out_size, void* d_ws, size_t ws_size,
                              hipStream_t stream) {
    const float* m      = (const float*)d_in[0];
    const int* edge_idx = (const int*)d_in[1];
    const float* W1     = (const float*)d_in[3];
    const float* b1     = (const float*)d_in[4];
    const float* W2     = (const float*)d_in[5];
    const float* b2     = (const float*)d_in[6];
    const float* Wlin   = (const float*)d_in[7];
    const float* blin   = (const float*)d_in[8];

    int E = in_sizes[0] / HDIM;
    int N = out_size / HDIM;
    const int* tgt = edge_idx + E;

    int nblk = (E + CHUNK - 1) >> CHUNK_LOG;   // 8192-edge chunks (62 for E=500k)

    // workspace layout (256B-aligned)
    char* ws = (char*)d_ws;
    size_t off = 0;
    auto align_up = [](size_t v) { return (v + 255) & ~(size_t)255; };

    __bf16* wbf = (__bf16*)(ws + off);
    off = align_up(off + (size_t)NSTAGE * HDIM * HDIM * sizeof(__bf16));
    unsigned short* rank = (unsigned short*)(ws + off);
    off = align_up(off + (size_t)E * sizeof(unsigned short));
    int* hb = (int*)(ws + off);
    off = align_up(off + (size_t)nblk * N * sizeof(int));
    int* tot = (int*)(ws + off);
    off = align_up(off + (size_t)N * sizeof(int));
    int* base = (int*)(ws + off);
    off = align_up(off + (size_t)N * sizeof(int));
    int* perm = (int*)(ws + off);
    off = align_up(off + (size_t)E * sizeof(int));
    int* snode = (int*)(ws + off);
    off = align_up(off + (size_t)E * sizeof(int));

    hipMemsetAsync(d_out, 0, (size_t)out_size * sizeof(float), stream);

    convert_weights<<<(NSTAGE * HDIM * HDIM + 255) / 256, 256, 0, stream>>>(W1, W2, Wlin, wbf);

    // atomic-free counting sort
    hist_rank_kernel<<<nblk, 1024, 0, stream>>>(tgt, rank, hb, E, N);
    colsum_kernel<<<(N + 255) / 256, 256, 0, stream>>>(hb, tot, nblk, N);
    scan_kernel<<<1, 1024, 0, stream>>>(tot, base, N);
    offsets_kernel<<<(N + 255) / 256, 256, 0, stream>>>(hb, base, nblk, N);
    emit_perm_kernel<<<(E + 255) / 256, 256, 0, stream>>>(tgt, rank, hb, perm, snode, E, N);

    int ntiles  = (E + 31) / 32;
    int nblocks = (ntiles + 3) / 4;
    fused_mlp_scatter<<<nblocks, 256, 0, stream>>>(m, perm, snode, wbf, b1, b2, blin,
                                                   (float*)d_out, E, ntiles);
}